// Round 10
// baseline (265.059 us; speedup 1.0000x reference)
//
#include <hip/hip_runtime.h>
#include <hip/hip_bf16.h>
#include <cstdint>
#include <cstddef>

using bf16 = __hip_bfloat16;
typedef __attribute__((ext_vector_type(8))) short short8;
typedef __attribute__((ext_vector_type(4))) short short4v;
typedef __attribute__((ext_vector_type(4))) float f32x4;

#define KQLD 2048             // qkv row stride (Q|K only; V routed to Vt)
#define SCL   0.18033688f     // 0.125 * log2(e): folded into Wq/bq
#define EXP2F(x) __builtin_amdgcn_exp2f(x)   // v_exp_f32 (D = 2^S0)

__device__ __forceinline__ void gl2lds16(const bf16* g, void* l) {
  __builtin_amdgcn_global_load_lds((const __attribute__((address_space(1))) void*)g,
                                   (__attribute__((address_space(3))) void*)l, 16, 0, 0);
}

// ---------------------------------------------------------------------------
// gemm_big: 512 threads, 128x256 tile, 8 waves (2Mx4N). TWO staging buffers
// (48KB LDS) -> 3 blocks/CU: all 768 QKV blocks co-resident (1.0 scheduling
// rounds, was 1.5 at 3-buf/72KB) and 24 waves/CU of barrier-decoupled
// latency hiding. Drain-to-0 pipeline (stage t+1, compute t, vmcnt(0)+
// barrier) -- per-step stall hidden by the 2 other resident blocks.
// VTM=1 routes cols >= 2048 (V) transposed into Vt[z][d][tok].
// ---------------------------------------------------------------------------
template<int ACT, bool OUTBF, bool HASB, int VTM>
__global__ __launch_bounds__(512)
void gemm_big(const bf16* __restrict__ A, const bf16* __restrict__ Bm,
              void* __restrict__ Cv, const float* __restrict__ bias,
              int N, int K, int lda, int ldb, int ldc, bf16* __restrict__ Vt)
{
  __shared__ __align__(16) short lA[2 * 4096];   // 2 bufs x 8KB  (128x32)
  __shared__ __align__(16) short lB[2 * 8192];   // 2 bufs x 16KB (256x32)
  const int tid = threadIdx.x;
  int bx = blockIdx.x, by = blockIdx.y;
  {
    const int nwg = gridDim.x * gridDim.y;
    if ((nwg & 7) == 0) {                    // bijective XCD chunking
      int n = by * gridDim.x + bx;
      n = (n & 7) * (nwg >> 3) + (n >> 3);
      bx = n / gridDim.y;                    // consecutive n share bx (A panel)
      by = n % gridDim.y;
    }
  }
  const int m0 = bx * 128;
  const int n0 = by * 256;
  const int w = tid >> 6, lane = tid & 63;
  const int wr = (w >> 2) * 64, wc = (w & 3) * 64;
  const int lr = lane & 15, lg = lane >> 4;
  f32x4 acc[4][4] = {};
  const int ra = tid >> 2;
  const int xc = ((tid & 3) ^ ((tid >> 2) & 3)) * 8;
  const int e1 = tid + 512;
  const int rb1 = e1 >> 2;
  const bf16* pa0 = A + (long)(m0 + ra) * lda + xc;
  const bf16* pb0 = Bm + (long)(n0 + ra) * ldb + xc;
  const bf16* pb1 = Bm + (long)(n0 + rb1) * ldb + xc;

  #define GSTG(k0_, ofa_, ofb_) do {                  \
    gl2lds16(pa0 + (k0_), &lA[(ofa_) + tid * 8]);     \
    gl2lds16(pb0 + (k0_), &lB[(ofb_) + tid * 8]);     \
    gl2lds16(pb1 + (k0_), &lB[(ofb_) + e1 * 8]);      \
  } while (0)

  const int nT = K >> 5;
  GSTG(0, 0, 0);
  asm volatile("s_waitcnt vmcnt(0)" ::: "memory");
  __builtin_amdgcn_s_barrier();
  __builtin_amdgcn_sched_barrier(0);

  const int lgx = (lg ^ (lr & 3)) * 8;     // swizzled chunk position (shorts)
  int oa = 0, oa1 = 4096;
  int ob = 0, ob1 = 8192;
  for (int t = 0; t < nT; ++t) {
    if (t + 1 < nT) GSTG((t + 1) * 32, oa1, ob1);
    short8 af[4], bfr[4];
    #pragma unroll
    for (int i = 0; i < 4; ++i) {
      af[i]  = *(const short8*)(&lA[oa + (wr + i * 16 + lr) * 32 + lgx]);
      bfr[i] = *(const short8*)(&lB[ob + (wc + i * 16 + lr) * 32 + lgx]);
    }
    #pragma unroll
    for (int mf = 0; mf < 4; ++mf)
      #pragma unroll
      for (int nf = 0; nf < 4; ++nf)
        acc[mf][nf] = __builtin_amdgcn_mfma_f32_16x16x32_bf16(af[mf], bfr[nf], acc[mf][nf], 0, 0, 0);
    if (t + 1 < nT) {
      asm volatile("s_waitcnt vmcnt(0)" ::: "memory");
      __builtin_amdgcn_s_barrier();
      __builtin_amdgcn_sched_barrier(0);
      int tmp = oa; oa = oa1; oa1 = tmp;
      tmp = ob; ob = ob1; ob1 = tmp;
    }
  }
  #undef GSTG

  #pragma unroll
  for (int nf = 0; nf < 4; ++nf) {
    const int col = n0 + wc + nf * 16 + lr;
    if (col >= N) continue;
    const float bv = HASB ? bias[col] : 0.0f;
    if (VTM && col >= 2048) {
      const int hd = col - 2048;
      const int d = hd & 63, hh = hd >> 6;
      #pragma unroll
      for (int mf = 0; mf < 4; ++mf) {
        const int row0 = m0 + wr + mf * 16 + lg * 4;
        const int zz = ((1 - (row0 >> 12)) << 7) | (((row0 >> 9) & 7) << 4) | hh;
        short4v pk;
        #pragma unroll
        for (int j = 0; j < 4; ++j)
          pk[j] = (short)__builtin_bit_cast(unsigned short,
                    __float2bfloat16(acc[mf][nf][j] + bv));
        *(short4v*)(Vt + ((long)(zz * 64 + d)) * 512 + (row0 & 511)) = pk;
      }
    } else {
      #pragma unroll
      for (int mf = 0; mf < 4; ++mf) {
        #pragma unroll
        for (int j = 0; j < 4; ++j) {
          const int row = m0 + wr + mf * 16 + lg * 4 + j;
          float x = acc[mf][nf][j] + bv;
          if (ACT == 1) x = tanhf(x);
          const long off = (long)row * ldc + col;
          if (OUTBF) ((bf16*)Cv)[off] = __float2bfloat16(x);
          else       ((float*)Cv)[off] = x;
        }
      }
    }
  }
}

// ---------------------------------------------------------------------------
// gemm_64: 64x128 tile, 256 threads (4 waves, each 64 rows x 32 cols),
// 3-buffer counted-vmcnt pipeline, 36KB LDS -> 4 blocks/CU (16 waves/CU).
// Wins when occupancy-starved AND B-panel fits per-XCD L2 (pooler: B=2MB).
// ---------------------------------------------------------------------------
template<int ACT, bool OUTBF>
__global__ __launch_bounds__(256)
void gemm_64(const bf16* __restrict__ A, const bf16* __restrict__ Bm,
             void* __restrict__ Cv, const float* __restrict__ bias,
             int K, int lda, int ldb, int ldc)
{
  __shared__ __align__(16) short lA[3 * 2048];   // 3 bufs x 4KB  (64x32)
  __shared__ __align__(16) short lB[3 * 4096];   // 3 bufs x 8KB  (128x32)
  const int tid = threadIdx.x;
  int bx = blockIdx.x, by = blockIdx.y;
  {
    const int nwg = gridDim.x * gridDim.y;
    if ((nwg & 7) == 0) {                    // bijective XCD chunking
      int n = by * gridDim.x + bx;
      n = (n & 7) * (nwg >> 3) + (n >> 3);
      bx = n / gridDim.y;
      by = n % gridDim.y;
    }
  }
  const int m0 = bx * 64;
  const int n0 = by * 128;
  const int w = tid >> 6, lane = tid & 63;
  const int wc = w * 32;
  const int lr = lane & 15, lg = lane >> 4;
  f32x4 acc[4][2] = {};
  const int rA = tid >> 2, cA = (tid & 3) * 8;
  const bf16* pa  = A + (long)(m0 + rA) * lda + cA;
  const bf16* pb0 = Bm + (long)(n0 + rA) * ldb + cA;
  const bf16* pb1 = Bm + (long)(n0 + 64 + rA) * ldb + cA;

  #define GS64(k0_, oa_, ob_) do {                     \
    gl2lds16(pa  + (k0_), &lA[(oa_) + tid * 8]);       \
    gl2lds16(pb0 + (k0_), &lB[(ob_) + tid * 8]);       \
    gl2lds16(pb1 + (k0_), &lB[(ob_) + 2048 + tid * 8]);\
  } while (0)

  const int nT = K >> 5;
  GS64(0, 0, 0);
  if (nT > 1) GS64(32, 2048, 4096);
  if (nT > 2) asm volatile("s_waitcnt vmcnt(3)" ::: "memory");
  else        asm volatile("s_waitcnt vmcnt(0)" ::: "memory");
  __builtin_amdgcn_s_barrier();
  __builtin_amdgcn_sched_barrier(0);

  int oa = 0, oa1 = 2048, oa2 = 4096;
  int ob = 0, ob1 = 4096, ob2 = 8192;
  for (int t = 0; t < nT; ++t) {
    if (t + 2 < nT) GS64((t + 2) * 32, oa2, ob2);
    short8 af[4], bfr[2];
    #pragma unroll
    for (int i = 0; i < 4; ++i)
      af[i] = *(const short8*)(&lA[oa + (i * 16 + lr) * 32 + lg * 8]);
    #pragma unroll
    for (int j = 0; j < 2; ++j)
      bfr[j] = *(const short8*)(&lB[ob + (wc + j * 16 + lr) * 32 + lg * 8]);
    #pragma unroll
    for (int mf = 0; mf < 4; ++mf)
      #pragma unroll
      for (int nf = 0; nf < 2; ++nf)
        acc[mf][nf] = __builtin_amdgcn_mfma_f32_16x16x32_bf16(af[mf], bfr[nf], acc[mf][nf], 0, 0, 0);
    if (t + 1 < nT) {
      if (t + 2 < nT) asm volatile("s_waitcnt vmcnt(3)" ::: "memory");
      else            asm volatile("s_waitcnt vmcnt(0)" ::: "memory");
      __builtin_amdgcn_s_barrier();
      __builtin_amdgcn_sched_barrier(0);
      int tmp = oa; oa = oa1; oa1 = oa2; oa2 = tmp;
      tmp = ob; ob = ob1; ob1 = ob2; ob2 = tmp;
    }
  }
  #undef GS64

  #pragma unroll
  for (int nf = 0; nf < 2; ++nf) {
    const int col = n0 + wc + nf * 16 + lr;
    const float bv = bias[col];
    #pragma unroll
    for (int mf = 0; mf < 4; ++mf) {
      #pragma unroll
      for (int j = 0; j < 4; ++j) {
        const int row = m0 + mf * 16 + lg * 4 + j;
        float x = acc[mf][nf][j] + bv;
        if (ACT == 1) x = tanhf(x);
        const long off = (long)row * ldc + col;
        if (OUTBF) ((bf16*)Cv)[off] = __float2bfloat16(x);
        else       ((float*)Cv)[off] = x;
      }
    }
  }
}

// ---------------------------------------------------------------------------
// gemm_32: 32x128 tile, 128 threads (2 waves, each 32 rows x 64 cols),
// 3-buffer counted-vmcnt pipeline, 30KB LDS. M=4096 tail GEMMs: 1024 blocks
// all co-resident (4/CU), 8 independent 2-wave streams per CU.
// ---------------------------------------------------------------------------
template<int ACT, bool OUTBF>
__global__ __launch_bounds__(128, 4)
void gemm_32(const bf16* __restrict__ A, const bf16* __restrict__ Bm,
             void* __restrict__ Cv, const float* __restrict__ bias,
             int K, int lda, int ldb, int ldc)
{
  __shared__ __align__(16) short lA[3 * 1024];   // 3 bufs x 2KB  (32x32)
  __shared__ __align__(16) short lB[3 * 4096];   // 3 bufs x 8KB  (128x32)
  const int tid = threadIdx.x;
  int bx = blockIdx.x, by = blockIdx.y;
  {
    const int nwg = gridDim.x * gridDim.y;
    if ((nwg & 7) == 0) {                    // bijective XCD chunking
      int n = by * gridDim.x + bx;
      n = (n & 7) * (nwg >> 3) + (n >> 3);
      bx = n / gridDim.y;
      by = n % gridDim.y;
    }
  }
  const int m0 = bx * 32;
  const int n0 = by * 128;
  const int w = tid >> 6, lane = tid & 63;
  const int wc = w * 64;
  const int lr = lane & 15, lg = lane >> 4;
  f32x4 acc[2][4] = {};
  const int rA = tid >> 2, cA = (tid & 3) * 8;   // rA 0..31
  const bf16* pa = A + (long)(m0 + rA) * lda + cA;
  const bf16* pb = Bm + (long)(n0 + rA) * ldb + cA;
  const long ldb32 = (long)ldb * 32;

  #define GS32(k0_, oa_, ob_) do {                                  \
    gl2lds16(pa + (k0_), &lA[(oa_) + tid * 8]);                     \
    gl2lds16(pb + (k0_),              &lB[(ob_) + tid * 8]);        \
    gl2lds16(pb + (k0_) + ldb32,      &lB[(ob_) + 1024 + tid * 8]); \
    gl2lds16(pb + (k0_) + 2 * ldb32,  &lB[(ob_) + 2048 + tid * 8]); \
    gl2lds16(pb + (k0_) + 3 * ldb32,  &lB[(ob_) + 3072 + tid * 8]); \
  } while (0)

  const int nT = K >> 5;
  GS32(0, 0, 0);
  if (nT > 1) GS32(32, 1024, 4096);
  if (nT > 2) asm volatile("s_waitcnt vmcnt(5)" ::: "memory");
  else        asm volatile("s_waitcnt vmcnt(0)" ::: "memory");
  __builtin_amdgcn_s_barrier();
  __builtin_amdgcn_sched_barrier(0);

  int oa = 0, oa1 = 1024, oa2 = 2048;
  int ob = 0, ob1 = 4096, ob2 = 8192;
  for (int t = 0; t < nT; ++t) {
    if (t + 2 < nT) GS32((t + 2) * 32, oa2, ob2);
    short8 af[2], bfr[4];
    #pragma unroll
    for (int i = 0; i < 2; ++i)
      af[i] = *(const short8*)(&lA[oa + (i * 16 + lr) * 32 + lg * 8]);
    #pragma unroll
    for (int j = 0; j < 4; ++j)
      bfr[j] = *(const short8*)(&lB[ob + (wc + j * 16 + lr) * 32 + lg * 8]);
    #pragma unroll
    for (int mf = 0; mf < 2; ++mf)
      #pragma unroll
      for (int nf = 0; nf < 4; ++nf)
        acc[mf][nf] = __builtin_amdgcn_mfma_f32_16x16x32_bf16(af[mf], bfr[nf], acc[mf][nf], 0, 0, 0);
    if (t + 1 < nT) {
      if (t + 2 < nT) asm volatile("s_waitcnt vmcnt(5)" ::: "memory");
      else            asm volatile("s_waitcnt vmcnt(0)" ::: "memory");
      __builtin_amdgcn_s_barrier();
      __builtin_amdgcn_sched_barrier(0);
      int tmp = oa; oa = oa1; oa1 = oa2; oa2 = tmp;
      tmp = ob; ob = ob1; ob1 = ob2; ob2 = tmp;
    }
  }
  #undef GS32

  #pragma unroll
  for (int nf = 0; nf < 4; ++nf) {
    const int col = n0 + wc + nf * 16 + lr;
    const float bv = bias[col];
    #pragma unroll
    for (int mf = 0; mf < 2; ++mf) {
      #pragma unroll
      for (int j = 0; j < 4; ++j) {
        const int row = m0 + mf * 16 + lg * 4 + j;
        float x = acc[mf][nf][j] + bv;
        if (ACT == 1) x = tanhf(x);
        const long off = (long)row * ldc + col;
        if (OUTBF) ((bf16*)Cv)[off] = __float2bfloat16(x);
        else       ((float*)Cv)[off] = x;
      }
    }
  }
}

// ---------------------------------------------------------------------------
// k_prep: one launch for weight-convert (5120 blocks), seq gather (8192),
// and table/bias init (1 block). bf16 outputs packed as short4v 8B stores.
// ---------------------------------------------------------------------------
__global__ __launch_bounds__(256)
void k_prep(const float* __restrict__ w0, const float* __restrict__ w1,
            const float* __restrict__ w2, const float* __restrict__ w3,
            const float* __restrict__ w4, bf16* __restrict__ wdst,
            const float* __restrict__ seq, const int* __restrict__ dl,
            const int* __restrict__ ql, const int* __restrict__ ol,
            bf16* __restrict__ X, bf16* __restrict__ tbl, bf16* __restrict__ tbt,
            const float* __restrict__ bq, const float* __restrict__ bk,
            const float* __restrict__ bv, float* __restrict__ biasq)
{
  const int bid = blockIdx.x, tid = threadIdx.x;
  if (bid < 5120) {
    const int bsel = bid >> 10;
    const float* s = bsel == 0 ? w0 : bsel == 1 ? w1 : bsel == 2 ? w2 : bsel == 3 ? w3 : w4;
    const float sc = (bsel == 0) ? SCL : 1.0f;
    const long loc = ((long)(bid & 1023) * 256 + tid) * 4;
    float4 v = *(const float4*)(s + loc);
    short4v pk;
    pk[0] = (short)__builtin_bit_cast(unsigned short, __float2bfloat16(v.x * sc));
    pk[1] = (short)__builtin_bit_cast(unsigned short, __float2bfloat16(v.y * sc));
    pk[2] = (short)__builtin_bit_cast(unsigned short, __float2bfloat16(v.z * sc));
    pk[3] = (short)__builtin_bit_cast(unsigned short, __float2bfloat16(v.w * sc));
    *(short4v*)(wdst + (long)bsel * 1048576 + loc) = pk;
  } else if (bid < 13312) {
    const int row = bid - 5120;
    const int c = tid * 4;
    const int b = (row >> 9) & 7, j = row & 511;
    int vlen, src;
    if (row < 4096) { vlen = dl[b]; src = (j + 1 > 511) ? 511 : j + 1; }
    else {
      vlen = ql[b] + ol[b];
      int s2 = j + dl[b] + 1;
      src = s2 > 511 ? 511 : (s2 < 0 ? 0 : s2);
    }
    float4 v = make_float4(0, 0, 0, 0);
    if (j < vlen) v = *(const float4*)(seq + ((long)b * 512 + src) * 1024 + c);
    short4v pk;
    pk[0] = (short)__builtin_bit_cast(unsigned short, __float2bfloat16(v.x));
    pk[1] = (short)__builtin_bit_cast(unsigned short, __float2bfloat16(v.y));
    pk[2] = (short)__builtin_bit_cast(unsigned short, __float2bfloat16(v.z));
    pk[3] = (short)__builtin_bit_cast(unsigned short, __float2bfloat16(v.w));
    *(short4v*)(X + (long)row * 1024 + c) = pk;
  } else {
    for (int idx = tid; idx < 144 * 64; idx += 256) {
      const int r = idx >> 6, d = idx & 63;
      float v = 0.0f;
      if (r < 129) {
        const float dv = powf(10000.0f, -(float)(d >> 1) / 32.0f);
        const float a = (float)r * dv;
        v = (d & 1) ? cosf(a) : sinf(a);
      }
      tbl[idx] = __float2bfloat16(v);
    }
    for (int idx = tid; idx < 64 * 160; idx += 256) {
      const int d = idx / 160, rr = idx % 160;
      float v = 0.0f;
      if (rr < 129) {
        const float dv = powf(10000.0f, -(float)(d >> 1) / 32.0f);
        const float a = (float)rr * dv;
        v = (d & 1) ? cosf(a) : sinf(a);
      }
      tbt[idx] = __float2bfloat16(v);
    }
    for (int idx = tid; idx < 3072; idx += 256) {
      float v = (idx < 1024) ? bq[idx] * SCL : (idx < 2048) ? bk[idx - 1024] : bv[idx - 2048];
      biasq[idx] = v;
    }
  }
}

// ---------------------------------------------------------------------------
// Fused NeZha attention (log2-domain, no max tracking). Proven 16-wave
// version: block owns 256 q-rows (4 qsegs) of one z; 32 KB K/V double-buffer
// amortized over 16 waves. Per-wave bias table (qrow) and band-P buffer
// MERGED into one [16][132] array (overlay-exact; see prior rounds).
// LDS 137216 B -> 16 waves/CU.
// ---------------------------------------------------------------------------
__global__ __launch_bounds__(1024, 4)
void k_attn(const bf16* __restrict__ QKV, const bf16* __restrict__ Vt,
            const bf16* __restrict__ tbl, const bf16* __restrict__ tbt,
            bf16* __restrict__ ctx)
{
  __shared__ __align__(16) unsigned short s_kv[16384];          // K0|K1|V0|V1 swizzled (32 KB)
  __shared__ __align__(16) unsigned short s_ptile[16][16 * 72]; // 36864 B
  __shared__ __align__(16) unsigned short s_m[16][16 * 132];    // qrow ∪ band, 67584 B

  const int tid = threadIdx.x;
  const int wv = tid >> 6, lane = tid & 63;
  const int lr = lane & 15, lg = lane >> 4;
  const int bid = blockIdx.x;
  const int xcd = bid & 7;
  const int idx = bid >> 3;                 // 0..63
  const int z = (xcd << 5) | (idx >> 1);    // 0..255; same-z pair on same XCD
  const int g = idx & 1;                    // which half of the 8 qsegs
  const int attn = z >> 7, b = (z >> 4) & 7, h = z & 15;
  const int qtok0 = attn * 4096 + b * 512;
  const int ktok0 = (1 - attn) * 4096 + b * 512;
  const int q0 = g * 256 + wv * 16;         // wave's 16 q-rows
  const int q = q0 + lr;

  unsigned short* ptile = s_ptile[wv];
  unsigned short* mrow  = s_m[wv];

  const bf16* Kbase = QKV + (long)ktok0 * KQLD + 1024 + h * 64;
  const bf16* Vbase = Vt + (long)z * (64 * 512);

  const int sl = tid & 511;
  const int rs = sl >> 3, cs = (sl & 7) * 8;
  const int scz = cs ^ ((rs & 7) << 3);
  const bool isV = tid >= 512;

  short8 qf[2];
  #pragma unroll
  for (int hh = 0; hh < 2; ++hh)
    qf[hh] = *(const short8*)(QKV + (long)(qtok0 + q0 + lr) * KQLD + h * 64 + hh * 32 + lg * 8);

  #define STAGE(kvb_, koff_, voff_) do {                                            \
    if (!isV) gl2lds16(Kbase + (long)((kvb_) + rs) * KQLD + scz, &s_kv[(koff_) + sl * 8]); \
    else      gl2lds16(Vbase + (long)rs * 512 + (kvb_) + scz,    &s_kv[(voff_) + sl * 8]); \
  } while (0)

  STAGE(0, 0, 8192);   // prologue: tile 0 -> buf0 (overlaps qR compute below)

  #pragma unroll
  for (int rt = 0; rt < 9; ++rt) {
    f32x4 qa = {};
    #pragma unroll
    for (int hh = 0; hh < 2; ++hh) {
      short8 ta = *(const short8*)(tbl + (rt * 16 + lr) * 64 + hh * 32 + lg * 8);
      qa = __builtin_amdgcn_mfma_f32_16x16x32_bf16(ta, qf[hh], qa, 0, 0, 0);
    }
    if (rt < 8 || lg == 0) {
      short4v pk;
      #pragma unroll
      for (int j = 0; j < 4; ++j)
        pk[j] = (short)__builtin_bit_cast(unsigned short, __float2bfloat16(qa[j]));
      *(short4v*)(&mrow[lr * 132 + rt * 16 + lg * 4]) = pk;
    }
  }

  const int hx = (lr >> 2) & 1;
  const int lgx8 = (lg ^ (lr & 3)) * 8;
  const int lrx64 = lr * 64;

  const float bias_lo = __bfloat162float(((const bf16*)mrow)[lr * 132 + 0]);
  const float bias_hi = __bfloat162float(((const bf16*)mrow)[lr * 132 + 128]);

  float l_run = 0.f, b0 = 0.f, b1 = 0.f;
  f32x4 cacc[4] = {};

  __syncthreads();   // tile 0 staged (vmcnt drained)

  #pragma unroll 2
  for (int t = 0; t < 8; ++t) {
    const int kvb = t * 64;
    const int koff = (t & 1) * 4096;
    const int voff = 8192 + koff;
    if (t < 7) { const int nk = ((t + 1) & 1) * 4096; STAGE(kvb + 64, nk, 8192 + nk); }

    f32x4 sc[4] = {};
    __builtin_amdgcn_s_setprio(1);
    #pragma unroll
    for (int hh = 0; hh < 2; ++hh) {
      const int cb = ((hh ^ hx) << 5) + lgx8;
      #pragma unroll
      for (int kb4 = 0; kb4 < 4; ++kb4) {
        short8 ak = *(const short8*)(&s_kv[koff + kb4 * 1024 + lrx64 + cb]);
        sc[kb4] = __builtin_amdgcn_mfma_f32_16x16x32_bf16(ak, qf[hh], sc[kb4], 0, 0, 0);
      }
    }
    __builtin_amdgcn_s_setprio(0);

    const int cls = (kvb + 63 <= q0 - 64) ? 0 : ((kvb >= q0 + 79) ? 2 : 1);

    float pacc[4];
    if (cls == 1) {
      const bool eLo = (kvb <= q0 - 49);
      const bool eHi = (kvb + 63 >= q0 + 64);
      short4v pks[4];
      #pragma unroll
      for (int kb4 = 0; kb4 < 4; ++kb4) {
        short4v pk;
        float ps = 0.f;
        #pragma unroll
        for (int j = 0; j < 4; ++j) {
          int rel = kvb + kb4 * 16 + 4 * lg + j - q;
          int rc = rel < -64 ? -64 : (rel > 64 ? 64 : rel);
          float bias = __bfloat162float(((const bf16*)mrow)[lr * 132 + rc + 64]);
          float p = EXP2F(sc[kb4][j] + bias);
          ps += p;
          if (eLo && rel <= -64) b0 += p;
          if (eHi && rel >= 64)  b1 += p;
          pk[j] = (short)__builtin_bit_cast(unsigned short, __float2bfloat16(p));
        }
        pks[kb4] = pk;
        pacc[kb4] = ps;
        *(short4v*)(&ptile[lr * 72 + kb4 * 16 + 4 * lg]) = pk;
      }
      l_run += (pacc[0] + pacc[1]) + (pacc[2] + pacc[3]);
      #pragma unroll
      for (int kb4 = 0; kb4 < 4; ++kb4)
        #pragma unroll
        for (int j = 0; j < 4; ++j) {
          int rel = kvb + kb4 * 16 + 4 * lg + j - q;
          if (rel > -64 && rel < 64)
            mrow[lr * 132 + rel + 63] = (unsigned short)pks[kb4][j];
        }
    } else {
      const float bc = (cls == 0) ? bias_lo : bias_hi;
      #pragma unroll
      for (int kb4 = 0; kb4 < 4; ++kb4) {
        short4v pk;
        float ps = 0.f;
        #pragma unroll
        for (int j = 0; j < 4; ++j) {
          float p = EXP2F(sc[kb4][j] + bc);
          ps += p;
          pk[j] = (short)__builtin_bit_cast(unsigned short, __float2bfloat16(p));
        }
        pacc[kb4] = ps;
        *(short4v*)(&ptile[lr * 72 + kb4 * 16 + 4 * lg]) = pk;
      }
      const float ts = (pacc[0] + pacc[1]) + (pacc[2] + pacc[3]);
      l_run += ts;
      if (cls == 0) b0 += ts; else b1 += ts;
    }

    __builtin_amdgcn_s_setprio(1);
    #pragma unroll
    for (int c2 = 0; c2 < 2; ++c2) {
      short8 pa = *(const short8*)(&ptile[lr * 72 + c2 * 32 + lg * 8]);
      const int cb = ((c2 ^ hx) << 5) + lgx8;
      #pragma unroll
      for (int nf = 0; nf < 4; ++nf) {
        short8 vb = *(const short8*)(&s_kv[voff + nf * 1024 + lrx64 + cb]);
        cacc[nf] = __builtin_amdgcn_mfma_f32_16x16x32_bf16(pa, vb, cacc[nf], 0, 0, 0);
      }
    }
    __builtin_amdgcn_s_setprio(0);
    __syncthreads();
  }
  #undef STAGE

  l_run += __shfl_xor(l_run, 16); l_run += __shfl_xor(l_run, 32);
  b0 += __shfl_xor(b0, 16); b0 += __shfl_xor(b0, 32);
  b1 += __shfl_xor(b1, 16); b1 += __shfl_xor(b1, 32);
  const float inv = 1.0f / l_run;

  #pragma unroll
  for (int j = 0; j < 4; ++j) {
    float iq = __shfl(inv, 4 * lg + j);
    #pragma unroll
    for (int nf = 0; nf < 4; ++nf) cacc[nf][j] *= iq;
  }
  short8 paf[5];
  #pragma unroll
  for (int c = 0; c < 5; ++c)
    #pragma unroll
    for (int j = 0; j < 8; ++j) {
      int r = c * 32 + 8 * lg + j;
      float v = 0.f;
      if (r == 0) v = b0;
      else if (r == 128) v = b1;
      else if (r < 128) {
        int k = q + r - 64;
        if (k >= 0 && k < 512)
          v = __bfloat162float(((const bf16*)mrow)[lr * 132 + r - 1]);
      }
      bf16 vb = __float2bfloat16(v * inv);
      paf[c][j] = (short)__builtin_bit_cast(unsigned short, vb);
    }
  __builtin_amdgcn_s_setprio(1);
  #pragma unroll
  for (int c = 0; c < 5; ++c)
    #pragma unroll
    for (int nf = 0; nf < 4; ++nf) {
      short8 tb = *(const short8*)(tbt + (nf * 16 + lr) * 160 + c * 32 + lg * 8);
      cacc[nf] = __builtin_amdgcn_mfma_f32_16x16x32_bf16(paf[c], tb, cacc[nf], 0, 0, 0);
    }
  __builtin_amdgcn_s_setprio(0);
  #pragma unroll
  for (int nf = 0; nf < 4; ++nf)
    #pragma unroll
    for (int j = 0; j < 4; ++j) {
      int qq = q0 + 4 * lg + j;
      ctx[(long)(qtok0 + qq) * 1024 + h * 64 + nf * 16 + lr] = __float2bfloat16(cacc[nf][j]);
    }
}

// LayerNorm over (y + qo_pooled), output bf16
__global__ __launch_bounds__(256) void k_ln(const float* __restrict__ y,
    const bf16* __restrict__ pooled, const float* __restrict__ g,
    const float* __restrict__ be, bf16* __restrict__ o)
{
  const int row = blockIdx.x, tid = threadIdx.x;
  float x[4], s1 = 0.0f, s2 = 0.0f;
  #pragma unroll
  for (int i = 0; i < 4; ++i) {
    const int c = tid + i * 256;
    x[i] = y[(long)row * 1024 + c] + __bfloat162float(pooled[(long)(4096 + row) * 1024 + c]);
    s1 += x[i]; s2 += x[i] * x[i];
  }
  #pragma unroll
  for (int off = 1; off < 64; off <<= 1) { s1 += __shfl_xor(s1, off); s2 += __shfl_xor(s2, off); }
  __shared__ float r1[4], r2[4];
  if ((tid & 63) == 0) { r1[tid >> 6] = s1; r2[tid >> 6] = s2; }
  __syncthreads();
  s1 = r1[0] + r1[1] + r1[2] + r1[3];
  s2 = r2[0] + r2[1] + r2[2] + r2[3];
  const float mu = s1 * (1.0f / 1024.0f);
  const float var = s2 * (1.0f / 1024.0f) - mu * mu;
  const float rs = rsqrtf(var + 1e-12f);
  #pragma unroll
  for (int i = 0; i < 4; ++i) {
    const int c = tid + i * 256;
    o[(long)row * 1024 + c] = __float2bfloat16((x[i] - mu) * rs * g[c] + be[c]);
  }
}

__global__ void k_sent(float* o, float v) { o[0] = v; }

// ---------------------------------------------------------------------------
extern "C" void kernel_launch(void* const* d_in, const int* in_sizes, int n_in,
                              void* d_out, int out_size, void* d_ws, size_t ws_size,
                              hipStream_t stream)
{
  (void)in_sizes; (void)n_in; (void)out_size;
  const float* seq = (const float*)d_in[0];
  const int*  dl = (const int*)d_in[1];
  const int*  ql = (const int*)d_in[2];
  const int*  ol = (const int*)d_in[3];
  const float* Wq = (const float*)d_in[4];  const float* bq = (const float*)d_in[5];
  const float* Wk = (const float*)d_in[6];  const float* bk = (const float*)d_in[7];
  const float* Wv = (const float*)d_in[8];  const float* bv = (const float*)d_in[9];
  const float* Wp = (const float*)d_in[10]; const float* bp = (const float*)d_in[11];
  const float* Wo = (const float*)d_in[12]; const float* bo = (const float*)d_in[13];
  const float* lng = (const float*)d_in[14]; const float* lnb = (const float*)d_in[15];
  float* out = (float*)d_out;
  char* ws = (char*)d_ws;

  size_t cur = 0;
  auto alloc = [&](size_t bts) { size_t o = cur; cur += (bts + 255) & ~(size_t)255; return o; };
  const size_t oBIAS = alloc(3072 * sizeof(float));
  const size_t oTBL  = alloc(144 * 64 * 2);
  const size_t oTBT  = alloc(64 * 160 * 2);
  const size_t oWBF  = alloc(5ull * 1048576 * 2);
  const size_t oXBF  = alloc(8192ull * 1024 * 2);
  const size_t oQKV  = alloc(8192ull * KQLD * 2);
  const size_t oQR   = alloc(8192ull * 2176 * 2);   // pooled + ybuf region
  const size_t oBP   = alloc(256ull * 64 * 512 * 2);
  if (ws_size < cur) {  // distinctive sentinel: absmax ~ 1e6 + ws MB
    k_sent<<<1, 1, 0, stream>>>(out, 1.0e6f + (float)(ws_size >> 20));
    return;
  }

  float* biasq = (float*)(ws + oBIAS);
  bf16* tbl = (bf16*)(ws + oTBL);
  bf16* tbt = (bf16*)(ws + oTBT);
  bf16* wqb = (bf16*)(ws + oWBF);
  bf16* wpb = wqb + 3 * 1048576;
  bf16* wob = wqb + 4 * 1048576;
  bf16* xbf = (bf16*)(ws + oXBF);
  bf16* qkv = (bf16*)(ws + oQKV);
  bf16* bpb = (bf16*)(ws + oBP);
  bf16* ctx = xbf;                                         // alias: X dead after QKV
  bf16* pooled = (bf16*)(ws + oQR);                        // qR region reuse
  float* ybuf = (float*)(ws + oQR + 8192ull * 1024 * 2);   // after pooled
  bf16* yln = (bf16*)(ws + oBP);                           // alias: Vt dead after attn

  dim3 blk(256);
  // prep: weights cvt + gather + tables/bias in one launch
  k_prep<<<13313, blk, 0, stream>>>(Wq, Wk, Wv, Wp, Wo, wqb,
                                    seq, dl, ql, ol, xbf, tbl, tbt,
                                    bq, bk, bv, biasq);

  // Fused QKV projection: 2-buf/48KB gemm_big -> 3 blocks/CU, all 768 blocks
  // co-resident (1.0 rounds). Q|K -> qkv (ldc=2048), V -> Vt (transposed).
  gemm_big<0, true, true, 1><<<dim3(64, 12, 1), dim3(512), 0, stream>>>(xbf, wqb, qkv, biasq, 3072, 1024, 1024, 1024, KQLD, bpb);
  // fused attention (qR computed in-kernel) -> ctx; 16 waves/block
  k_attn<<<512, dim3(1024), 0, stream>>>(qkv, bpb, tbl, tbt, ctx);

  // poolers on both halves at once: tanh(ctx Wp^T + bp); 1024 blocks = 4/CU
  gemm_64<1, true><<<dim3(128, 8, 1), blk, 0, stream>>>(ctx, wpb, pooled, bp, 1024, 1024, 1024, 1024);
  // y = doc_pooled Wo^T + bo  (f32); 1024 blocks of 2 waves, all co-resident
  gemm_32<0, false><<<dim3(128, 8, 1), dim3(128), 0, stream>>>(pooled, wob, ybuf, bo, 1024, 1024, 1024, 1024);
  // LayerNorm(y + qo_pooled)
  k_ln<<<4096, blk, 0, stream>>>(ybuf, pooled, lng, lnb, yln);
  // out = tanh(yln Wp^T + bp)  (f32 to d_out); 1024 blocks of 2 waves
  gemm_32<1, false><<<dim3(128, 8, 1), dim3(128), 0, stream>>>(yln, wpb, out, bp, 1024, 1024, 1024, 1024);
}

// Round 11
// 263.795 us; speedup vs baseline: 1.0048x; 1.0048x over previous
//
#include <hip/hip_runtime.h>
#include <hip/hip_bf16.h>
#include <cstdint>
#include <cstddef>

using bf16 = __hip_bfloat16;
typedef __attribute__((ext_vector_type(8))) short short8;
typedef __attribute__((ext_vector_type(4))) short short4v;
typedef __attribute__((ext_vector_type(4))) float f32x4;

#define KQLD 2048             // qkv row stride (Q|K only; V routed to Vt)
#define SCL   0.18033688f     // 0.125 * log2(e): folded into Wq/bq
#define EXP2F(x) __builtin_amdgcn_exp2f(x)   // v_exp_f32 (D = 2^S0)

__device__ __forceinline__ void gl2lds16(const bf16* g, void* l) {
  __builtin_amdgcn_global_load_lds((const __attribute__((address_space(1))) void*)g,
                                   (__attribute__((address_space(3))) void*)l, 16, 0, 0);
}

// ---------------------------------------------------------------------------
// gemm_big: 512 threads, 128x256 tile, 8 waves (2Mx4N), 3-buffer counted-vmcnt
// pipeline (72KB LDS, 2 blocks/CU). Best measured QKV structure (75.6-76.7us
// across the session; 2-buf/48KB did NOT raise occupancy -- packer caps
// 512-thread groups at 2/CU). B-panel (6MB > per-XCD L2) read M/128 = 64x;
// MFMA:ds_read = 2.0. VTM=1 routes cols >= 2048 (V) transposed into
// Vt[z][d][tok]. XCD-chunked block swizzle (T1).
// ---------------------------------------------------------------------------
template<int ACT, bool OUTBF, bool HASB, int VTM>
__global__ __launch_bounds__(512)
void gemm_big(const bf16* __restrict__ A, const bf16* __restrict__ Bm,
              void* __restrict__ Cv, const float* __restrict__ bias,
              int N, int K, int lda, int ldb, int ldc, bf16* __restrict__ Vt)
{
  __shared__ __align__(16) short lA[3 * 4096];   // 3 bufs x 8KB  (128x32)
  __shared__ __align__(16) short lB[3 * 8192];   // 3 bufs x 16KB (256x32)
  const int tid = threadIdx.x;
  int bx = blockIdx.x, by = blockIdx.y;
  {
    const int nwg = gridDim.x * gridDim.y;
    if ((nwg & 7) == 0) {                    // bijective XCD chunking
      int n = by * gridDim.x + bx;
      n = (n & 7) * (nwg >> 3) + (n >> 3);
      bx = n / gridDim.y;                    // consecutive n share bx (A panel)
      by = n % gridDim.y;
    }
  }
  const int m0 = bx * 128;
  const int n0 = by * 256;
  const int w = tid >> 6, lane = tid & 63;
  const int wr = (w >> 2) * 64, wc = (w & 3) * 64;
  const int lr = lane & 15, lg = lane >> 4;
  f32x4 acc[4][4] = {};
  const int ra = tid >> 2;
  const int xc = ((tid & 3) ^ ((tid >> 2) & 3)) * 8;
  const int e1 = tid + 512;
  const int rb1 = e1 >> 2;
  const bf16* pa0 = A + (long)(m0 + ra) * lda + xc;
  const bf16* pb0 = Bm + (long)(n0 + ra) * ldb + xc;
  const bf16* pb1 = Bm + (long)(n0 + rb1) * ldb + xc;

  #define GSTG(k0_, ofa_, ofb_) do {                  \
    gl2lds16(pa0 + (k0_), &lA[(ofa_) + tid * 8]);     \
    gl2lds16(pb0 + (k0_), &lB[(ofb_) + tid * 8]);     \
    gl2lds16(pb1 + (k0_), &lB[(ofb_) + e1 * 8]);      \
  } while (0)

  const int nT = K >> 5;
  GSTG(0, 0, 0);
  if (nT > 1) GSTG(32, 4096, 8192);
  if (nT > 2) asm volatile("s_waitcnt vmcnt(3)" ::: "memory");
  else        asm volatile("s_waitcnt vmcnt(0)" ::: "memory");
  __builtin_amdgcn_s_barrier();
  __builtin_amdgcn_sched_barrier(0);

  const int lgx = (lg ^ (lr & 3)) * 8;     // swizzled chunk position (shorts)
  int oa = 0, oa1 = 4096, oa2 = 8192;
  int ob = 0, ob1 = 8192, ob2 = 16384;
  for (int t = 0; t < nT; ++t) {
    if (t + 2 < nT) GSTG((t + 2) * 32, oa2, ob2);
    short8 af[4], bfr[4];
    #pragma unroll
    for (int i = 0; i < 4; ++i) {
      af[i]  = *(const short8*)(&lA[oa + (wr + i * 16 + lr) * 32 + lgx]);
      bfr[i] = *(const short8*)(&lB[ob + (wc + i * 16 + lr) * 32 + lgx]);
    }
    #pragma unroll
    for (int mf = 0; mf < 4; ++mf)
      #pragma unroll
      for (int nf = 0; nf < 4; ++nf)
        acc[mf][nf] = __builtin_amdgcn_mfma_f32_16x16x32_bf16(af[mf], bfr[nf], acc[mf][nf], 0, 0, 0);
    if (t + 1 < nT) {
      if (t + 2 < nT) asm volatile("s_waitcnt vmcnt(3)" ::: "memory");
      else            asm volatile("s_waitcnt vmcnt(0)" ::: "memory");
      __builtin_amdgcn_s_barrier();
      __builtin_amdgcn_sched_barrier(0);
      int tmp = oa; oa = oa1; oa1 = oa2; oa2 = tmp;
      tmp = ob; ob = ob1; ob1 = ob2; ob2 = tmp;
    }
  }
  #undef GSTG

  #pragma unroll
  for (int nf = 0; nf < 4; ++nf) {
    const int col = n0 + wc + nf * 16 + lr;
    if (col >= N) continue;
    const float bv = HASB ? bias[col] : 0.0f;
    if (VTM && col >= 2048) {
      const int hd = col - 2048;
      const int d = hd & 63, hh = hd >> 6;
      #pragma unroll
      for (int mf = 0; mf < 4; ++mf) {
        const int row0 = m0 + wr + mf * 16 + lg * 4;
        const int zz = ((1 - (row0 >> 12)) << 7) | (((row0 >> 9) & 7) << 4) | hh;
        short4v pk;
        #pragma unroll
        for (int j = 0; j < 4; ++j)
          pk[j] = (short)__builtin_bit_cast(unsigned short,
                    __float2bfloat16(acc[mf][nf][j] + bv));
        *(short4v*)(Vt + ((long)(zz * 64 + d)) * 512 + (row0 & 511)) = pk;
      }
    } else {
      #pragma unroll
      for (int mf = 0; mf < 4; ++mf) {
        #pragma unroll
        for (int j = 0; j < 4; ++j) {
          const int row = m0 + wr + mf * 16 + lg * 4 + j;
          float x = acc[mf][nf][j] + bv;
          if (ACT == 1) x = tanhf(x);
          const long off = (long)row * ldc + col;
          if (OUTBF) ((bf16*)Cv)[off] = __float2bfloat16(x);
          else       ((float*)Cv)[off] = x;
        }
      }
    }
  }
}

// ---------------------------------------------------------------------------
// gemm_64: 64x128 tile, 256 threads (4 waves, each 64 rows x 32 cols),
// 3-buffer counted-vmcnt pipeline, 36KB LDS -> 4 blocks/CU (16 waves/CU).
// ~1.7x faster per FLOP than the 128-row structure on the tail GEMMs
// (latency-bound regime; B-panel 2MB is per-XCD-L2-resident).
// ---------------------------------------------------------------------------
template<int ACT, bool OUTBF>
__global__ __launch_bounds__(256)
void gemm_64(const bf16* __restrict__ A, const bf16* __restrict__ Bm,
             void* __restrict__ Cv, const float* __restrict__ bias,
             int K, int lda, int ldb, int ldc)
{
  __shared__ __align__(16) short lA[3 * 2048];   // 3 bufs x 4KB  (64x32)
  __shared__ __align__(16) short lB[3 * 4096];   // 3 bufs x 8KB  (128x32)
  const int tid = threadIdx.x;
  int bx = blockIdx.x, by = blockIdx.y;
  {
    const int nwg = gridDim.x * gridDim.y;
    if ((nwg & 7) == 0) {                    // bijective XCD chunking
      int n = by * gridDim.x + bx;
      n = (n & 7) * (nwg >> 3) + (n >> 3);
      bx = n / gridDim.y;
      by = n % gridDim.y;
    }
  }
  const int m0 = bx * 64;
  const int n0 = by * 128;
  const int w = tid >> 6, lane = tid & 63;
  const int wc = w * 32;
  const int lr = lane & 15, lg = lane >> 4;
  f32x4 acc[4][2] = {};
  const int rA = tid >> 2, cA = (tid & 3) * 8;
  const bf16* pa  = A + (long)(m0 + rA) * lda + cA;
  const bf16* pb0 = Bm + (long)(n0 + rA) * ldb + cA;
  const bf16* pb1 = Bm + (long)(n0 + 64 + rA) * ldb + cA;

  #define GS64(k0_, oa_, ob_) do {                     \
    gl2lds16(pa  + (k0_), &lA[(oa_) + tid * 8]);       \
    gl2lds16(pb0 + (k0_), &lB[(ob_) + tid * 8]);       \
    gl2lds16(pb1 + (k0_), &lB[(ob_) + 2048 + tid * 8]);\
  } while (0)

  const int nT = K >> 5;
  GS64(0, 0, 0);
  if (nT > 1) GS64(32, 2048, 4096);
  if (nT > 2) asm volatile("s_waitcnt vmcnt(3)" ::: "memory");
  else        asm volatile("s_waitcnt vmcnt(0)" ::: "memory");
  __builtin_amdgcn_s_barrier();
  __builtin_amdgcn_sched_barrier(0);

  int oa = 0, oa1 = 2048, oa2 = 4096;
  int ob = 0, ob1 = 4096, ob2 = 8192;
  for (int t = 0; t < nT; ++t) {
    if (t + 2 < nT) GS64((t + 2) * 32, oa2, ob2);
    short8 af[4], bfr[2];
    #pragma unroll
    for (int i = 0; i < 4; ++i)
      af[i] = *(const short8*)(&lA[oa + (i * 16 + lr) * 32 + lg * 8]);
    #pragma unroll
    for (int j = 0; j < 2; ++j)
      bfr[j] = *(const short8*)(&lB[ob + (wc + j * 16 + lr) * 32 + lg * 8]);
    #pragma unroll
    for (int mf = 0; mf < 4; ++mf)
      #pragma unroll
      for (int nf = 0; nf < 2; ++nf)
        acc[mf][nf] = __builtin_amdgcn_mfma_f32_16x16x32_bf16(af[mf], bfr[nf], acc[mf][nf], 0, 0, 0);
    if (t + 1 < nT) {
      if (t + 2 < nT) asm volatile("s_waitcnt vmcnt(3)" ::: "memory");
      else            asm volatile("s_waitcnt vmcnt(0)" ::: "memory");
      __builtin_amdgcn_s_barrier();
      __builtin_amdgcn_sched_barrier(0);
      int tmp = oa; oa = oa1; oa1 = oa2; oa2 = tmp;
      tmp = ob; ob = ob1; ob1 = ob2; ob2 = tmp;
    }
  }
  #undef GS64

  #pragma unroll
  for (int nf = 0; nf < 2; ++nf) {
    const int col = n0 + wc + nf * 16 + lr;
    const float bv = bias[col];
    #pragma unroll
    for (int mf = 0; mf < 4; ++mf) {
      #pragma unroll
      for (int j = 0; j < 4; ++j) {
        const int row = m0 + mf * 16 + lg * 4 + j;
        float x = acc[mf][nf][j] + bv;
        if (ACT == 1) x = tanhf(x);
        const long off = (long)row * ldc + col;
        if (OUTBF) ((bf16*)Cv)[off] = __float2bfloat16(x);
        else       ((float*)Cv)[off] = x;
      }
    }
  }
}

// ---------------------------------------------------------------------------
// k_prep: one launch for weight-convert (5120 blocks), seq gather (8192),
// and table/bias init (1 block). bf16 outputs packed as short4v 8B stores.
// ---------------------------------------------------------------------------
__global__ __launch_bounds__(256)
void k_prep(const float* __restrict__ w0, const float* __restrict__ w1,
            const float* __restrict__ w2, const float* __restrict__ w3,
            const float* __restrict__ w4, bf16* __restrict__ wdst,
            const float* __restrict__ seq, const int* __restrict__ dl,
            const int* __restrict__ ql, const int* __restrict__ ol,
            bf16* __restrict__ X, bf16* __restrict__ tbl, bf16* __restrict__ tbt,
            const float* __restrict__ bq, const float* __restrict__ bk,
            const float* __restrict__ bv, float* __restrict__ biasq)
{
  const int bid = blockIdx.x, tid = threadIdx.x;
  if (bid < 5120) {
    const int bsel = bid >> 10;
    const float* s = bsel == 0 ? w0 : bsel == 1 ? w1 : bsel == 2 ? w2 : bsel == 3 ? w3 : w4;
    const float sc = (bsel == 0) ? SCL : 1.0f;
    const long loc = ((long)(bid & 1023) * 256 + tid) * 4;
    float4 v = *(const float4*)(s + loc);
    short4v pk;
    pk[0] = (short)__builtin_bit_cast(unsigned short, __float2bfloat16(v.x * sc));
    pk[1] = (short)__builtin_bit_cast(unsigned short, __float2bfloat16(v.y * sc));
    pk[2] = (short)__builtin_bit_cast(unsigned short, __float2bfloat16(v.z * sc));
    pk[3] = (short)__builtin_bit_cast(unsigned short, __float2bfloat16(v.w * sc));
    *(short4v*)(wdst + (long)bsel * 1048576 + loc) = pk;
  } else if (bid < 13312) {
    const int row = bid - 5120;
    const int c = tid * 4;
    const int b = (row >> 9) & 7, j = row & 511;
    int vlen, src;
    if (row < 4096) { vlen = dl[b]; src = (j + 1 > 511) ? 511 : j + 1; }
    else {
      vlen = ql[b] + ol[b];
      int s2 = j + dl[b] + 1;
      src = s2 > 511 ? 511 : (s2 < 0 ? 0 : s2);
    }
    float4 v = make_float4(0, 0, 0, 0);
    if (j < vlen) v = *(const float4*)(seq + ((long)b * 512 + src) * 1024 + c);
    short4v pk;
    pk[0] = (short)__builtin_bit_cast(unsigned short, __float2bfloat16(v.x));
    pk[1] = (short)__builtin_bit_cast(unsigned short, __float2bfloat16(v.y));
    pk[2] = (short)__builtin_bit_cast(unsigned short, __float2bfloat16(v.z));
    pk[3] = (short)__builtin_bit_cast(unsigned short, __float2bfloat16(v.w));
    *(short4v*)(X + (long)row * 1024 + c) = pk;
  } else {
    for (int idx = tid; idx < 144 * 64; idx += 256) {
      const int r = idx >> 6, d = idx & 63;
      float v = 0.0f;
      if (r < 129) {
        const float dv = powf(10000.0f, -(float)(d >> 1) / 32.0f);
        const float a = (float)r * dv;
        v = (d & 1) ? cosf(a) : sinf(a);
      }
      tbl[idx] = __float2bfloat16(v);
    }
    for (int idx = tid; idx < 64 * 160; idx += 256) {
      const int d = idx / 160, rr = idx % 160;
      float v = 0.0f;
      if (rr < 129) {
        const float dv = powf(10000.0f, -(float)(d >> 1) / 32.0f);
        const float a = (float)rr * dv;
        v = (d & 1) ? cosf(a) : sinf(a);
      }
      tbt[idx] = __float2bfloat16(v);
    }
    for (int idx = tid; idx < 3072; idx += 256) {
      float v = (idx < 1024) ? bq[idx] * SCL : (idx < 2048) ? bk[idx - 1024] : bv[idx - 2048];
      biasq[idx] = v;
    }
  }
}

// ---------------------------------------------------------------------------
// Fused NeZha attention (log2-domain, no max tracking). Proven 16-wave
// version: block owns 256 q-rows (4 qsegs) of one z; 32 KB K/V double-buffer
// amortized over 16 waves. Per-wave bias table (qrow) and band-P buffer
// MERGED into one [16][132] array (overlay-exact; see prior rounds).
// LDS 137216 B -> 16 waves/CU.
// ---------------------------------------------------------------------------
__global__ __launch_bounds__(1024, 4)
void k_attn(const bf16* __restrict__ QKV, const bf16* __restrict__ Vt,
            const bf16* __restrict__ tbl, const bf16* __restrict__ tbt,
            bf16* __restrict__ ctx)
{
  __shared__ __align__(16) unsigned short s_kv[16384];          // K0|K1|V0|V1 swizzled (32 KB)
  __shared__ __align__(16) unsigned short s_ptile[16][16 * 72]; // 36864 B
  __shared__ __align__(16) unsigned short s_m[16][16 * 132];    // qrow ∪ band, 67584 B

  const int tid = threadIdx.x;
  const int wv = tid >> 6, lane = tid & 63;
  const int lr = lane & 15, lg = lane >> 4;
  const int bid = blockIdx.x;
  const int xcd = bid & 7;
  const int idx = bid >> 3;                 // 0..63
  const int z = (xcd << 5) | (idx >> 1);    // 0..255; same-z pair on same XCD
  const int g = idx & 1;                    // which half of the 8 qsegs
  const int attn = z >> 7, b = (z >> 4) & 7, h = z & 15;
  const int qtok0 = attn * 4096 + b * 512;
  const int ktok0 = (1 - attn) * 4096 + b * 512;
  const int q0 = g * 256 + wv * 16;         // wave's 16 q-rows
  const int q = q0 + lr;

  unsigned short* ptile = s_ptile[wv];
  unsigned short* mrow  = s_m[wv];

  const bf16* Kbase = QKV + (long)ktok0 * KQLD + 1024 + h * 64;
  const bf16* Vbase = Vt + (long)z * (64 * 512);

  const int sl = tid & 511;
  const int rs = sl >> 3, cs = (sl & 7) * 8;
  const int scz = cs ^ ((rs & 7) << 3);
  const bool isV = tid >= 512;

  short8 qf[2];
  #pragma unroll
  for (int hh = 0; hh < 2; ++hh)
    qf[hh] = *(const short8*)(QKV + (long)(qtok0 + q0 + lr) * KQLD + h * 64 + hh * 32 + lg * 8);

  #define STAGE(kvb_, koff_, voff_) do {                                            \
    if (!isV) gl2lds16(Kbase + (long)((kvb_) + rs) * KQLD + scz, &s_kv[(koff_) + sl * 8]); \
    else      gl2lds16(Vbase + (long)rs * 512 + (kvb_) + scz,    &s_kv[(voff_) + sl * 8]); \
  } while (0)

  STAGE(0, 0, 8192);   // prologue: tile 0 -> buf0 (overlaps qR compute below)

  #pragma unroll
  for (int rt = 0; rt < 9; ++rt) {
    f32x4 qa = {};
    #pragma unroll
    for (int hh = 0; hh < 2; ++hh) {
      short8 ta = *(const short8*)(tbl + (rt * 16 + lr) * 64 + hh * 32 + lg * 8);
      qa = __builtin_amdgcn_mfma_f32_16x16x32_bf16(ta, qf[hh], qa, 0, 0, 0);
    }
    if (rt < 8 || lg == 0) {
      short4v pk;
      #pragma unroll
      for (int j = 0; j < 4; ++j)
        pk[j] = (short)__builtin_bit_cast(unsigned short, __float2bfloat16(qa[j]));
      *(short4v*)(&mrow[lr * 132 + rt * 16 + lg * 4]) = pk;
    }
  }

  const int hx = (lr >> 2) & 1;
  const int lgx8 = (lg ^ (lr & 3)) * 8;
  const int lrx64 = lr * 64;

  const float bias_lo = __bfloat162float(((const bf16*)mrow)[lr * 132 + 0]);
  const float bias_hi = __bfloat162float(((const bf16*)mrow)[lr * 132 + 128]);

  float l_run = 0.f, b0 = 0.f, b1 = 0.f;
  f32x4 cacc[4] = {};

  __syncthreads();   // tile 0 staged (vmcnt drained)

  #pragma unroll 2
  for (int t = 0; t < 8; ++t) {
    const int kvb = t * 64;
    const int koff = (t & 1) * 4096;
    const int voff = 8192 + koff;
    if (t < 7) { const int nk = ((t + 1) & 1) * 4096; STAGE(kvb + 64, nk, 8192 + nk); }

    f32x4 sc[4] = {};
    __builtin_amdgcn_s_setprio(1);
    #pragma unroll
    for (int hh = 0; hh < 2; ++hh) {
      const int cb = ((hh ^ hx) << 5) + lgx8;
      #pragma unroll
      for (int kb4 = 0; kb4 < 4; ++kb4) {
        short8 ak = *(const short8*)(&s_kv[koff + kb4 * 1024 + lrx64 + cb]);
        sc[kb4] = __builtin_amdgcn_mfma_f32_16x16x32_bf16(ak, qf[hh], sc[kb4], 0, 0, 0);
      }
    }
    __builtin_amdgcn_s_setprio(0);

    const int cls = (kvb + 63 <= q0 - 64) ? 0 : ((kvb >= q0 + 79) ? 2 : 1);

    float pacc[4];
    if (cls == 1) {
      const bool eLo = (kvb <= q0 - 49);
      const bool eHi = (kvb + 63 >= q0 + 64);
      short4v pks[4];
      #pragma unroll
      for (int kb4 = 0; kb4 < 4; ++kb4) {
        short4v pk;
        float ps = 0.f;
        #pragma unroll
        for (int j = 0; j < 4; ++j) {
          int rel = kvb + kb4 * 16 + 4 * lg + j - q;
          int rc = rel < -64 ? -64 : (rel > 64 ? 64 : rel);
          float bias = __bfloat162float(((const bf16*)mrow)[lr * 132 + rc + 64]);
          float p = EXP2F(sc[kb4][j] + bias);
          ps += p;
          if (eLo && rel <= -64) b0 += p;
          if (eHi && rel >= 64)  b1 += p;
          pk[j] = (short)__builtin_bit_cast(unsigned short, __float2bfloat16(p));
        }
        pks[kb4] = pk;
        pacc[kb4] = ps;
        *(short4v*)(&ptile[lr * 72 + kb4 * 16 + 4 * lg]) = pk;
      }
      l_run += (pacc[0] + pacc[1]) + (pacc[2] + pacc[3]);
      #pragma unroll
      for (int kb4 = 0; kb4 < 4; ++kb4)
        #pragma unroll
        for (int j = 0; j < 4; ++j) {
          int rel = kvb + kb4 * 16 + 4 * lg + j - q;
          if (rel > -64 && rel < 64)
            mrow[lr * 132 + rel + 63] = (unsigned short)pks[kb4][j];
        }
    } else {
      const float bc = (cls == 0) ? bias_lo : bias_hi;
      #pragma unroll
      for (int kb4 = 0; kb4 < 4; ++kb4) {
        short4v pk;
        float ps = 0.f;
        #pragma unroll
        for (int j = 0; j < 4; ++j) {
          float p = EXP2F(sc[kb4][j] + bc);
          ps += p;
          pk[j] = (short)__builtin_bit_cast(unsigned short, __float2bfloat16(p));
        }
        pacc[kb4] = ps;
        *(short4v*)(&ptile[lr * 72 + kb4 * 16 + 4 * lg]) = pk;
      }
      const float ts = (pacc[0] + pacc[1]) + (pacc[2] + pacc[3]);
      l_run += ts;
      if (cls == 0) b0 += ts; else b1 += ts;
    }

    __builtin_amdgcn_s_setprio(1);
    #pragma unroll
    for (int c2 = 0; c2 < 2; ++c2) {
      short8 pa = *(const short8*)(&ptile[lr * 72 + c2 * 32 + lg * 8]);
      const int cb = ((c2 ^ hx) << 5) + lgx8;
      #pragma unroll
      for (int nf = 0; nf < 4; ++nf) {
        short8 vb = *(const short8*)(&s_kv[voff + nf * 1024 + lrx64 + cb]);
        cacc[nf] = __builtin_amdgcn_mfma_f32_16x16x32_bf16(pa, vb, cacc[nf], 0, 0, 0);
      }
    }
    __builtin_amdgcn_s_setprio(0);
    __syncthreads();
  }
  #undef STAGE

  l_run += __shfl_xor(l_run, 16); l_run += __shfl_xor(l_run, 32);
  b0 += __shfl_xor(b0, 16); b0 += __shfl_xor(b0, 32);
  b1 += __shfl_xor(b1, 16); b1 += __shfl_xor(b1, 32);
  const float inv = 1.0f / l_run;

  #pragma unroll
  for (int j = 0; j < 4; ++j) {
    float iq = __shfl(inv, 4 * lg + j);
    #pragma unroll
    for (int nf = 0; nf < 4; ++nf) cacc[nf][j] *= iq;
  }
  short8 paf[5];
  #pragma unroll
  for (int c = 0; c < 5; ++c)
    #pragma unroll
    for (int j = 0; j < 8; ++j) {
      int r = c * 32 + 8 * lg + j;
      float v = 0.f;
      if (r == 0) v = b0;
      else if (r == 128) v = b1;
      else if (r < 128) {
        int k = q + r - 64;
        if (k >= 0 && k < 512)
          v = __bfloat162float(((const bf16*)mrow)[lr * 132 + r - 1]);
      }
      bf16 vb = __float2bfloat16(v * inv);
      paf[c][j] = (short)__builtin_bit_cast(unsigned short, vb);
    }
  __builtin_amdgcn_s_setprio(1);
  #pragma unroll
  for (int c = 0; c < 5; ++c)
    #pragma unroll
    for (int nf = 0; nf < 4; ++nf) {
      short8 tb = *(const short8*)(tbt + (nf * 16 + lr) * 160 + c * 32 + lg * 8);
      cacc[nf] = __builtin_amdgcn_mfma_f32_16x16x32_bf16(paf[c], tb, cacc[nf], 0, 0, 0);
    }
  __builtin_amdgcn_s_setprio(0);
  #pragma unroll
  for (int nf = 0; nf < 4; ++nf)
    #pragma unroll
    for (int j = 0; j < 4; ++j) {
      int qq = q0 + 4 * lg + j;
      ctx[(long)(qtok0 + qq) * 1024 + h * 64 + nf * 16 + lr] = __float2bfloat16(cacc[nf][j]);
    }
}

// LayerNorm over (y + qo_pooled), output bf16
__global__ __launch_bounds__(256) void k_ln(const float* __restrict__ y,
    const bf16* __restrict__ pooled, const float* __restrict__ g,
    const float* __restrict__ be, bf16* __restrict__ o)
{
  const int row = blockIdx.x, tid = threadIdx.x;
  float x[4], s1 = 0.0f, s2 = 0.0f;
  #pragma unroll
  for (int i = 0; i < 4; ++i) {
    const int c = tid + i * 256;
    x[i] = y[(long)row * 1024 + c] + __bfloat162float(pooled[(long)(4096 + row) * 1024 + c]);
    s1 += x[i]; s2 += x[i] * x[i];
  }
  #pragma unroll
  for (int off = 1; off < 64; off <<= 1) { s1 += __shfl_xor(s1, off); s2 += __shfl_xor(s2, off); }
  __shared__ float r1[4], r2[4];
  if ((tid & 63) == 0) { r1[tid >> 6] = s1; r2[tid >> 6] = s2; }
  __syncthreads();
  s1 = r1[0] + r1[1] + r1[2] + r1[3];
  s2 = r2[0] + r2[1] + r2[2] + r2[3];
  const float mu = s1 * (1.0f / 1024.0f);
  const float var = s2 * (1.0f / 1024.0f) - mu * mu;
  const float rs = rsqrtf(var + 1e-12f);
  #pragma unroll
  for (int i = 0; i < 4; ++i) {
    const int c = tid + i * 256;
    o[(long)row * 1024 + c] = __float2bfloat16((x[i] - mu) * rs * g[c] + be[c]);
  }
}

__global__ void k_sent(float* o, float v) { o[0] = v; }

// ---------------------------------------------------------------------------
extern "C" void kernel_launch(void* const* d_in, const int* in_sizes, int n_in,
                              void* d_out, int out_size, void* d_ws, size_t ws_size,
                              hipStream_t stream)
{
  (void)in_sizes; (void)n_in; (void)out_size;
  const float* seq = (const float*)d_in[0];
  const int*  dl = (const int*)d_in[1];
  const int*  ql = (const int*)d_in[2];
  const int*  ol = (const int*)d_in[3];
  const float* Wq = (const float*)d_in[4];  const float* bq = (const float*)d_in[5];
  const float* Wk = (const float*)d_in[6];  const float* bk = (const float*)d_in[7];
  const float* Wv = (const float*)d_in[8];  const float* bv = (const float*)d_in[9];
  const float* Wp = (const float*)d_in[10]; const float* bp = (const float*)d_in[11];
  const float* Wo = (const float*)d_in[12]; const float* bo = (const float*)d_in[13];
  const float* lng = (const float*)d_in[14]; const float* lnb = (const float*)d_in[15];
  float* out = (float*)d_out;
  char* ws = (char*)d_ws;

  size_t cur = 0;
  auto alloc = [&](size_t bts) { size_t o = cur; cur += (bts + 255) & ~(size_t)255; return o; };
  const size_t oBIAS = alloc(3072 * sizeof(float));
  const size_t oTBL  = alloc(144 * 64 * 2);
  const size_t oTBT  = alloc(64 * 160 * 2);
  const size_t oWBF  = alloc(5ull * 1048576 * 2);
  const size_t oXBF  = alloc(8192ull * 1024 * 2);
  const size_t oQKV  = alloc(8192ull * KQLD * 2);
  const size_t oQR   = alloc(8192ull * 2176 * 2);   // pooled + ybuf region
  const size_t oBP   = alloc(256ull * 64 * 512 * 2);
  if (ws_size < cur) {  // distinctive sentinel: absmax ~ 1e6 + ws MB
    k_sent<<<1, 1, 0, stream>>>(out, 1.0e6f + (float)(ws_size >> 20));
    return;
  }

  float* biasq = (float*)(ws + oBIAS);
  bf16* tbl = (bf16*)(ws + oTBL);
  bf16* tbt = (bf16*)(ws + oTBT);
  bf16* wqb = (bf16*)(ws + oWBF);
  bf16* wpb = wqb + 3 * 1048576;
  bf16* wob = wqb + 4 * 1048576;
  bf16* xbf = (bf16*)(ws + oXBF);
  bf16* qkv = (bf16*)(ws + oQKV);
  bf16* bpb = (bf16*)(ws + oBP);
  bf16* ctx = xbf;                                         // alias: X dead after QKV
  bf16* pooled = (bf16*)(ws + oQR);                        // qR region reuse
  float* ybuf = (float*)(ws + oQR + 8192ull * 1024 * 2);   // after pooled
  bf16* yln = (bf16*)(ws + oBP);                           // alias: Vt dead after attn

  dim3 blk(256);
  // prep: weights cvt + gather + tables/bias in one launch
  k_prep<<<13313, blk, 0, stream>>>(Wq, Wk, Wv, Wp, Wo, wqb,
                                    seq, dl, ql, ol, xbf, tbl, tbt,
                                    bq, bk, bv, biasq);

  // Fused QKV projection (best measured: 3-buf gemm_big): Q|K -> qkv
  // (ldc=2048), V -> Vt (transposed epilogue)
  gemm_big<0, true, true, 1><<<dim3(64, 12, 1), dim3(512), 0, stream>>>(xbf, wqb, qkv, biasq, 3072, 1024, 1024, 1024, KQLD, bpb);
  // fused attention (qR computed in-kernel) -> ctx; 16 waves/block
  k_attn<<<512, dim3(1024), 0, stream>>>(qkv, bpb, tbl, tbt, ctx);

  // poolers on both halves at once: tanh(ctx Wp^T + bp); 1024 blocks = 4/CU
  gemm_64<1, true><<<dim3(128, 8, 1), blk, 0, stream>>>(ctx, wpb, pooled, bp, 1024, 1024, 1024, 1024);
  // y = doc_pooled Wo^T + bo  (f32); 512 blocks
  gemm_64<0, false><<<dim3(64, 8, 1), blk, 0, stream>>>(pooled, wob, ybuf, bo, 1024, 1024, 1024, 1024);
  // LayerNorm(y + qo_pooled)
  k_ln<<<4096, blk, 0, stream>>>(ybuf, pooled, lng, lnb, yln);
  // out = tanh(yln Wp^T + bp)  (f32 to d_out); 512 blocks
  gemm_64<1, false><<<dim3(64, 8, 1), blk, 0, stream>>>(yln, wpb, out, bp, 1024, 1024, 1024, 1024);
}

// Round 12
// 236.663 us; speedup vs baseline: 1.1200x; 1.1146x over previous
//
#include <hip/hip_runtime.h>
#include <hip/hip_bf16.h>
#include <cstdint>
#include <cstddef>

using bf16 = __hip_bfloat16;
typedef __attribute__((ext_vector_type(8))) short short8;
typedef __attribute__((ext_vector_type(4))) short short4v;
typedef __attribute__((ext_vector_type(4))) float f32x4;

#define KQLD 2048             // qkv row stride (Q|K only; V routed to Vt)
#define SCL   0.18033688f     // 0.125 * log2(e): folded into Wq/bq
#define EXP2F(x) __builtin_amdgcn_exp2f(x)   // v_exp_f32 (D = 2^S0)

__device__ __forceinline__ void gl2lds16(const bf16* g, void* l) {
  __builtin_amdgcn_global_load_lds((const __attribute__((address_space(1))) void*)g,
                                   (__attribute__((address_space(3))) void*)l, 16, 0, 0);
}

// ---------------------------------------------------------------------------
// gemm_big: 512 threads, 128x256 tile, 8 waves (2Mx4N), 3-buffer counted-vmcnt
// pipeline (72KB LDS, 2 blocks/CU). VTM=1 (QKV): cols >= 2048 (V) go
// transposed into Vt[z][d][tok], and ZERO-TILE SKIP is enabled: the gather
// zeroes X rows j >= vlen (doc_len<300, ques+opt<199), so an M-tile whose
// first row j0 >= vlen is all-zero -> output is bit-exactly bias. Such blocks
// (~57% of the grid) skip the whole K-pipeline (wave-uniform branch) and
// emit bias directly. XCD-chunked block swizzle (T1).
// ---------------------------------------------------------------------------
template<int ACT, bool OUTBF, bool HASB, int VTM>
__global__ __launch_bounds__(512)
void gemm_big(const bf16* __restrict__ A, const bf16* __restrict__ Bm,
              void* __restrict__ Cv, const float* __restrict__ bias,
              int N, int K, int lda, int ldb, int ldc, bf16* __restrict__ Vt,
              const int* __restrict__ dl, const int* __restrict__ ql,
              const int* __restrict__ ol)
{
  __shared__ __align__(16) short lA[3 * 4096];   // 3 bufs x 8KB  (128x32)
  __shared__ __align__(16) short lB[3 * 8192];   // 3 bufs x 16KB (256x32)
  const int tid = threadIdx.x;
  int bx = blockIdx.x, by = blockIdx.y;
  {
    const int nwg = gridDim.x * gridDim.y;
    if ((nwg & 7) == 0) {                    // bijective XCD chunking
      int n = by * gridDim.x + bx;
      n = (n & 7) * (nwg >> 3) + (n >> 3);
      bx = n / gridDim.y;                    // consecutive n share bx (A panel)
      by = n % gridDim.y;
    }
  }
  const int m0 = bx * 128;
  const int n0 = by * 256;
  const int w = tid >> 6, lane = tid & 63;
  const int wr = (w >> 2) * 64, wc = (w & 3) * 64;
  const int lr = lane & 15, lg = lane >> 4;
  f32x4 acc[4][4] = {};

  // ---- zero-tile skip (QKV only): all 128 rows of this tile are zero in X
  // when the tile's first token index j0 >= vlen of its (half,b) segment.
  // Output then equals bias exactly (MFMA of exact zeros) -> skip K-loop.
  bool live = true;
  if (VTM) {
    const int half = m0 >> 12, bb = (m0 >> 9) & 7, j0 = m0 & 511;
    const int vlen = (half == 0) ? dl[bb] : (ql[bb] + ol[bb]);
    live = (j0 < vlen);
  }

  if (live) {
    const int ra = tid >> 2;
    const int xc = ((tid & 3) ^ ((tid >> 2) & 3)) * 8;
    const int e1 = tid + 512;
    const int rb1 = e1 >> 2;
    const bf16* pa0 = A + (long)(m0 + ra) * lda + xc;
    const bf16* pb0 = Bm + (long)(n0 + ra) * ldb + xc;
    const bf16* pb1 = Bm + (long)(n0 + rb1) * ldb + xc;

    #define GSTG(k0_, ofa_, ofb_) do {                  \
      gl2lds16(pa0 + (k0_), &lA[(ofa_) + tid * 8]);     \
      gl2lds16(pb0 + (k0_), &lB[(ofb_) + tid * 8]);     \
      gl2lds16(pb1 + (k0_), &lB[(ofb_) + e1 * 8]);      \
    } while (0)

    const int nT = K >> 5;
    GSTG(0, 0, 0);
    if (nT > 1) GSTG(32, 4096, 8192);
    if (nT > 2) asm volatile("s_waitcnt vmcnt(3)" ::: "memory");
    else        asm volatile("s_waitcnt vmcnt(0)" ::: "memory");
    __builtin_amdgcn_s_barrier();
    __builtin_amdgcn_sched_barrier(0);

    const int lgx = (lg ^ (lr & 3)) * 8;   // swizzled chunk position (shorts)
    int oa = 0, oa1 = 4096, oa2 = 8192;
    int ob = 0, ob1 = 8192, ob2 = 16384;
    for (int t = 0; t < nT; ++t) {
      if (t + 2 < nT) GSTG((t + 2) * 32, oa2, ob2);
      short8 af[4], bfr[4];
      #pragma unroll
      for (int i = 0; i < 4; ++i) {
        af[i]  = *(const short8*)(&lA[oa + (wr + i * 16 + lr) * 32 + lgx]);
        bfr[i] = *(const short8*)(&lB[ob + (wc + i * 16 + lr) * 32 + lgx]);
      }
      #pragma unroll
      for (int mf = 0; mf < 4; ++mf)
        #pragma unroll
        for (int nf = 0; nf < 4; ++nf)
          acc[mf][nf] = __builtin_amdgcn_mfma_f32_16x16x32_bf16(af[mf], bfr[nf], acc[mf][nf], 0, 0, 0);
      if (t + 1 < nT) {
        if (t + 2 < nT) asm volatile("s_waitcnt vmcnt(3)" ::: "memory");
        else            asm volatile("s_waitcnt vmcnt(0)" ::: "memory");
        __builtin_amdgcn_s_barrier();
        __builtin_amdgcn_sched_barrier(0);
        int tmp = oa; oa = oa1; oa1 = oa2; oa2 = tmp;
        tmp = ob; ob = ob1; ob1 = ob2; ob2 = tmp;
      }
    }
    #undef GSTG
  }

  #pragma unroll
  for (int nf = 0; nf < 4; ++nf) {
    const int col = n0 + wc + nf * 16 + lr;
    if (col >= N) continue;
    const float bv = HASB ? bias[col] : 0.0f;
    if (VTM && col >= 2048) {
      const int hd = col - 2048;
      const int d = hd & 63, hh = hd >> 6;
      #pragma unroll
      for (int mf = 0; mf < 4; ++mf) {
        const int row0 = m0 + wr + mf * 16 + lg * 4;
        const int zz = ((1 - (row0 >> 12)) << 7) | (((row0 >> 9) & 7) << 4) | hh;
        short4v pk;
        #pragma unroll
        for (int j = 0; j < 4; ++j)
          pk[j] = (short)__builtin_bit_cast(unsigned short,
                    __float2bfloat16(acc[mf][nf][j] + bv));
        *(short4v*)(Vt + ((long)(zz * 64 + d)) * 512 + (row0 & 511)) = pk;
      }
    } else {
      #pragma unroll
      for (int mf = 0; mf < 4; ++mf) {
        #pragma unroll
        for (int j = 0; j < 4; ++j) {
          const int row = m0 + wr + mf * 16 + lg * 4 + j;
          float x = acc[mf][nf][j] + bv;
          if (ACT == 1) x = tanhf(x);
          const long off = (long)row * ldc + col;
          if (OUTBF) ((bf16*)Cv)[off] = __float2bfloat16(x);
          else       ((float*)Cv)[off] = x;
        }
      }
    }
  }
}

// ---------------------------------------------------------------------------
// gemm_64: 64x128 tile, 256 threads (4 waves, each 64 rows x 32 cols),
// 3-buffer counted-vmcnt pipeline, 36KB LDS -> 4 blocks/CU (16 waves/CU).
// ~1.7x faster per FLOP than the 128-row structure on the tail GEMMs
// (latency-bound regime; B-panel 2MB is per-XCD-L2-resident).
// ---------------------------------------------------------------------------
template<int ACT, bool OUTBF>
__global__ __launch_bounds__(256)
void gemm_64(const bf16* __restrict__ A, const bf16* __restrict__ Bm,
             void* __restrict__ Cv, const float* __restrict__ bias,
             int K, int lda, int ldb, int ldc)
{
  __shared__ __align__(16) short lA[3 * 2048];   // 3 bufs x 4KB  (64x32)
  __shared__ __align__(16) short lB[3 * 4096];   // 3 bufs x 8KB  (128x32)
  const int tid = threadIdx.x;
  int bx = blockIdx.x, by = blockIdx.y;
  {
    const int nwg = gridDim.x * gridDim.y;
    if ((nwg & 7) == 0) {                    // bijective XCD chunking
      int n = by * gridDim.x + bx;
      n = (n & 7) * (nwg >> 3) + (n >> 3);
      bx = n / gridDim.y;
      by = n % gridDim.y;
    }
  }
  const int m0 = bx * 64;
  const int n0 = by * 128;
  const int w = tid >> 6, lane = tid & 63;
  const int wc = w * 32;
  const int lr = lane & 15, lg = lane >> 4;
  f32x4 acc[4][2] = {};
  const int rA = tid >> 2, cA = (tid & 3) * 8;
  const bf16* pa  = A + (long)(m0 + rA) * lda + cA;
  const bf16* pb0 = Bm + (long)(n0 + rA) * ldb + cA;
  const bf16* pb1 = Bm + (long)(n0 + 64 + rA) * ldb + cA;

  #define GS64(k0_, oa_, ob_) do {                     \
    gl2lds16(pa  + (k0_), &lA[(oa_) + tid * 8]);       \
    gl2lds16(pb0 + (k0_), &lB[(ob_) + tid * 8]);       \
    gl2lds16(pb1 + (k0_), &lB[(ob_) + 2048 + tid * 8]);\
  } while (0)

  const int nT = K >> 5;
  GS64(0, 0, 0);
  if (nT > 1) GS64(32, 2048, 4096);
  if (nT > 2) asm volatile("s_waitcnt vmcnt(3)" ::: "memory");
  else        asm volatile("s_waitcnt vmcnt(0)" ::: "memory");
  __builtin_amdgcn_s_barrier();
  __builtin_amdgcn_sched_barrier(0);

  int oa = 0, oa1 = 2048, oa2 = 4096;
  int ob = 0, ob1 = 4096, ob2 = 8192;
  for (int t = 0; t < nT; ++t) {
    if (t + 2 < nT) GS64((t + 2) * 32, oa2, ob2);
    short8 af[4], bfr[2];
    #pragma unroll
    for (int i = 0; i < 4; ++i)
      af[i] = *(const short8*)(&lA[oa + (i * 16 + lr) * 32 + lg * 8]);
    #pragma unroll
    for (int j = 0; j < 2; ++j)
      bfr[j] = *(const short8*)(&lB[ob + (wc + j * 16 + lr) * 32 + lg * 8]);
    #pragma unroll
    for (int mf = 0; mf < 4; ++mf)
      #pragma unroll
      for (int nf = 0; nf < 2; ++nf)
        acc[mf][nf] = __builtin_amdgcn_mfma_f32_16x16x32_bf16(af[mf], bfr[nf], acc[mf][nf], 0, 0, 0);
    if (t + 1 < nT) {
      if (t + 2 < nT) asm volatile("s_waitcnt vmcnt(3)" ::: "memory");
      else            asm volatile("s_waitcnt vmcnt(0)" ::: "memory");
      __builtin_amdgcn_s_barrier();
      __builtin_amdgcn_sched_barrier(0);
      int tmp = oa; oa = oa1; oa1 = oa2; oa2 = tmp;
      tmp = ob; ob = ob1; ob1 = ob2; ob2 = tmp;
    }
  }
  #undef GS64

  #pragma unroll
  for (int nf = 0; nf < 2; ++nf) {
    const int col = n0 + wc + nf * 16 + lr;
    const float bv = bias[col];
    #pragma unroll
    for (int mf = 0; mf < 4; ++mf) {
      #pragma unroll
      for (int j = 0; j < 4; ++j) {
        const int row = m0 + mf * 16 + lg * 4 + j;
        float x = acc[mf][nf][j] + bv;
        if (ACT == 1) x = tanhf(x);
        const long off = (long)row * ldc + col;
        if (OUTBF) ((bf16*)Cv)[off] = __float2bfloat16(x);
        else       ((float*)Cv)[off] = x;
      }
    }
  }
}

// ---------------------------------------------------------------------------
// k_prep: one launch for weight-convert (5120 blocks), seq gather (8192),
// and table/bias init (1 block). bf16 outputs packed as short4v 8B stores.
// ---------------------------------------------------------------------------
__global__ __launch_bounds__(256)
void k_prep(const float* __restrict__ w0, const float* __restrict__ w1,
            const float* __restrict__ w2, const float* __restrict__ w3,
            const float* __restrict__ w4, bf16* __restrict__ wdst,
            const float* __restrict__ seq, const int* __restrict__ dl,
            const int* __restrict__ ql, const int* __restrict__ ol,
            bf16* __restrict__ X, bf16* __restrict__ tbl, bf16* __restrict__ tbt,
            const float* __restrict__ bq, const float* __restrict__ bk,
            const float* __restrict__ bv, float* __restrict__ biasq)
{
  const int bid = blockIdx.x, tid = threadIdx.x;
  if (bid < 5120) {
    const int bsel = bid >> 10;
    const float* s = bsel == 0 ? w0 : bsel == 1 ? w1 : bsel == 2 ? w2 : bsel == 3 ? w3 : w4;
    const float sc = (bsel == 0) ? SCL : 1.0f;
    const long loc = ((long)(bid & 1023) * 256 + tid) * 4;
    float4 v = *(const float4*)(s + loc);
    short4v pk;
    pk[0] = (short)__builtin_bit_cast(unsigned short, __float2bfloat16(v.x * sc));
    pk[1] = (short)__builtin_bit_cast(unsigned short, __float2bfloat16(v.y * sc));
    pk[2] = (short)__builtin_bit_cast(unsigned short, __float2bfloat16(v.z * sc));
    pk[3] = (short)__builtin_bit_cast(unsigned short, __float2bfloat16(v.w * sc));
    *(short4v*)(wdst + (long)bsel * 1048576 + loc) = pk;
  } else if (bid < 13312) {
    const int row = bid - 5120;
    const int c = tid * 4;
    const int b = (row >> 9) & 7, j = row & 511;
    int vlen, src;
    if (row < 4096) { vlen = dl[b]; src = (j + 1 > 511) ? 511 : j + 1; }
    else {
      vlen = ql[b] + ol[b];
      int s2 = j + dl[b] + 1;
      src = s2 > 511 ? 511 : (s2 < 0 ? 0 : s2);
    }
    float4 v = make_float4(0, 0, 0, 0);
    if (j < vlen) v = *(const float4*)(seq + ((long)b * 512 + src) * 1024 + c);
    short4v pk;
    pk[0] = (short)__builtin_bit_cast(unsigned short, __float2bfloat16(v.x));
    pk[1] = (short)__builtin_bit_cast(unsigned short, __float2bfloat16(v.y));
    pk[2] = (short)__builtin_bit_cast(unsigned short, __float2bfloat16(v.z));
    pk[3] = (short)__builtin_bit_cast(unsigned short, __float2bfloat16(v.w));
    *(short4v*)(X + (long)row * 1024 + c) = pk;
  } else {
    for (int idx = tid; idx < 144 * 64; idx += 256) {
      const int r = idx >> 6, d = idx & 63;
      float v = 0.0f;
      if (r < 129) {
        const float dv = powf(10000.0f, -(float)(d >> 1) / 32.0f);
        const float a = (float)r * dv;
        v = (d & 1) ? cosf(a) : sinf(a);
      }
      tbl[idx] = __float2bfloat16(v);
    }
    for (int idx = tid; idx < 64 * 160; idx += 256) {
      const int d = idx / 160, rr = idx % 160;
      float v = 0.0f;
      if (rr < 129) {
        const float dv = powf(10000.0f, -(float)(d >> 1) / 32.0f);
        const float a = (float)rr * dv;
        v = (d & 1) ? cosf(a) : sinf(a);
      }
      tbt[idx] = __float2bfloat16(v);
    }
    for (int idx = tid; idx < 3072; idx += 256) {
      float v = (idx < 1024) ? bq[idx] * SCL : (idx < 2048) ? bk[idx - 1024] : bv[idx - 2048];
      biasq[idx] = v;
    }
  }
}

// ---------------------------------------------------------------------------
// Fused NeZha attention (log2-domain, no max tracking). Proven 16-wave
// version: block owns 256 q-rows (4 qsegs) of one z; 32 KB K/V double-buffer
// amortized over 16 waves. Per-wave bias table (qrow) and band-P buffer
// MERGED into one [16][132] array (overlay-exact; see prior rounds).
// LDS 137216 B -> 16 waves/CU.
// ---------------------------------------------------------------------------
__global__ __launch_bounds__(1024, 4)
void k_attn(const bf16* __restrict__ QKV, const bf16* __restrict__ Vt,
            const bf16* __restrict__ tbl, const bf16* __restrict__ tbt,
            bf16* __restrict__ ctx)
{
  __shared__ __align__(16) unsigned short s_kv[16384];          // K0|K1|V0|V1 swizzled (32 KB)
  __shared__ __align__(16) unsigned short s_ptile[16][16 * 72]; // 36864 B
  __shared__ __align__(16) unsigned short s_m[16][16 * 132];    // qrow ∪ band, 67584 B

  const int tid = threadIdx.x;
  const int wv = tid >> 6, lane = tid & 63;
  const int lr = lane & 15, lg = lane >> 4;
  const int bid = blockIdx.x;
  const int xcd = bid & 7;
  const int idx = bid >> 3;                 // 0..63
  const int z = (xcd << 5) | (idx >> 1);    // 0..255; same-z pair on same XCD
  const int g = idx & 1;                    // which half of the 8 qsegs
  const int attn = z >> 7, b = (z >> 4) & 7, h = z & 15;
  const int qtok0 = attn * 4096 + b * 512;
  const int ktok0 = (1 - attn) * 4096 + b * 512;
  const int q0 = g * 256 + wv * 16;         // wave's 16 q-rows
  const int q = q0 + lr;

  unsigned short* ptile = s_ptile[wv];
  unsigned short* mrow  = s_m[wv];

  const bf16* Kbase = QKV + (long)ktok0 * KQLD + 1024 + h * 64;
  const bf16* Vbase = Vt + (long)z * (64 * 512);

  const int sl = tid & 511;
  const int rs = sl >> 3, cs = (sl & 7) * 8;
  const int scz = cs ^ ((rs & 7) << 3);
  const bool isV = tid >= 512;

  short8 qf[2];
  #pragma unroll
  for (int hh = 0; hh < 2; ++hh)
    qf[hh] = *(const short8*)(QKV + (long)(qtok0 + q0 + lr) * KQLD + h * 64 + hh * 32 + lg * 8);

  #define STAGE(kvb_, koff_, voff_) do {                                            \
    if (!isV) gl2lds16(Kbase + (long)((kvb_) + rs) * KQLD + scz, &s_kv[(koff_) + sl * 8]); \
    else      gl2lds16(Vbase + (long)rs * 512 + (kvb_) + scz,    &s_kv[(voff_) + sl * 8]); \
  } while (0)

  STAGE(0, 0, 8192);   // prologue: tile 0 -> buf0 (overlaps qR compute below)

  #pragma unroll
  for (int rt = 0; rt < 9; ++rt) {
    f32x4 qa = {};
    #pragma unroll
    for (int hh = 0; hh < 2; ++hh) {
      short8 ta = *(const short8*)(tbl + (rt * 16 + lr) * 64 + hh * 32 + lg * 8);
      qa = __builtin_amdgcn_mfma_f32_16x16x32_bf16(ta, qf[hh], qa, 0, 0, 0);
    }
    if (rt < 8 || lg == 0) {
      short4v pk;
      #pragma unroll
      for (int j = 0; j < 4; ++j)
        pk[j] = (short)__builtin_bit_cast(unsigned short, __float2bfloat16(qa[j]));
      *(short4v*)(&mrow[lr * 132 + rt * 16 + lg * 4]) = pk;
    }
  }

  const int hx = (lr >> 2) & 1;
  const int lgx8 = (lg ^ (lr & 3)) * 8;
  const int lrx64 = lr * 64;

  const float bias_lo = __bfloat162float(((const bf16*)mrow)[lr * 132 + 0]);
  const float bias_hi = __bfloat162float(((const bf16*)mrow)[lr * 132 + 128]);

  float l_run = 0.f, b0 = 0.f, b1 = 0.f;
  f32x4 cacc[4] = {};

  __syncthreads();   // tile 0 staged (vmcnt drained)

  #pragma unroll 2
  for (int t = 0; t < 8; ++t) {
    const int kvb = t * 64;
    const int koff = (t & 1) * 4096;
    const int voff = 8192 + koff;
    if (t < 7) { const int nk = ((t + 1) & 1) * 4096; STAGE(kvb + 64, nk, 8192 + nk); }

    f32x4 sc[4] = {};
    __builtin_amdgcn_s_setprio(1);
    #pragma unroll
    for (int hh = 0; hh < 2; ++hh) {
      const int cb = ((hh ^ hx) << 5) + lgx8;
      #pragma unroll
      for (int kb4 = 0; kb4 < 4; ++kb4) {
        short8 ak = *(const short8*)(&s_kv[koff + kb4 * 1024 + lrx64 + cb]);
        sc[kb4] = __builtin_amdgcn_mfma_f32_16x16x32_bf16(ak, qf[hh], sc[kb4], 0, 0, 0);
      }
    }
    __builtin_amdgcn_s_setprio(0);

    const int cls = (kvb + 63 <= q0 - 64) ? 0 : ((kvb >= q0 + 79) ? 2 : 1);

    float pacc[4];
    if (cls == 1) {
      const bool eLo = (kvb <= q0 - 49);
      const bool eHi = (kvb + 63 >= q0 + 64);
      short4v pks[4];
      #pragma unroll
      for (int kb4 = 0; kb4 < 4; ++kb4) {
        short4v pk;
        float ps = 0.f;
        #pragma unroll
        for (int j = 0; j < 4; ++j) {
          int rel = kvb + kb4 * 16 + 4 * lg + j - q;
          int rc = rel < -64 ? -64 : (rel > 64 ? 64 : rel);
          float bias = __bfloat162float(((const bf16*)mrow)[lr * 132 + rc + 64]);
          float p = EXP2F(sc[kb4][j] + bias);
          ps += p;
          if (eLo && rel <= -64) b0 += p;
          if (eHi && rel >= 64)  b1 += p;
          pk[j] = (short)__builtin_bit_cast(unsigned short, __float2bfloat16(p));
        }
        pks[kb4] = pk;
        pacc[kb4] = ps;
        *(short4v*)(&ptile[lr * 72 + kb4 * 16 + 4 * lg]) = pk;
      }
      l_run += (pacc[0] + pacc[1]) + (pacc[2] + pacc[3]);
      #pragma unroll
      for (int kb4 = 0; kb4 < 4; ++kb4)
        #pragma unroll
        for (int j = 0; j < 4; ++j) {
          int rel = kvb + kb4 * 16 + 4 * lg + j - q;
          if (rel > -64 && rel < 64)
            mrow[lr * 132 + rel + 63] = (unsigned short)pks[kb4][j];
        }
    } else {
      const float bc = (cls == 0) ? bias_lo : bias_hi;
      #pragma unroll
      for (int kb4 = 0; kb4 < 4; ++kb4) {
        short4v pk;
        float ps = 0.f;
        #pragma unroll
        for (int j = 0; j < 4; ++j) {
          float p = EXP2F(sc[kb4][j] + bc);
          ps += p;
          pk[j] = (short)__builtin_bit_cast(unsigned short, __float2bfloat16(p));
        }
        pacc[kb4] = ps;
        *(short4v*)(&ptile[lr * 72 + kb4 * 16 + 4 * lg]) = pk;
      }
      const float ts = (pacc[0] + pacc[1]) + (pacc[2] + pacc[3]);
      l_run += ts;
      if (cls == 0) b0 += ts; else b1 += ts;
    }

    __builtin_amdgcn_s_setprio(1);
    #pragma unroll
    for (int c2 = 0; c2 < 2; ++c2) {
      short8 pa = *(const short8*)(&ptile[lr * 72 + c2 * 32 + lg * 8]);
      const int cb = ((c2 ^ hx) << 5) + lgx8;
      #pragma unroll
      for (int nf = 0; nf < 4; ++nf) {
        short8 vb = *(const short8*)(&s_kv[voff + nf * 1024 + lrx64 + cb]);
        cacc[nf] = __builtin_amdgcn_mfma_f32_16x16x32_bf16(pa, vb, cacc[nf], 0, 0, 0);
      }
    }
    __builtin_amdgcn_s_setprio(0);
    __syncthreads();
  }
  #undef STAGE

  l_run += __shfl_xor(l_run, 16); l_run += __shfl_xor(l_run, 32);
  b0 += __shfl_xor(b0, 16); b0 += __shfl_xor(b0, 32);
  b1 += __shfl_xor(b1, 16); b1 += __shfl_xor(b1, 32);
  const float inv = 1.0f / l_run;

  #pragma unroll
  for (int j = 0; j < 4; ++j) {
    float iq = __shfl(inv, 4 * lg + j);
    #pragma unroll
    for (int nf = 0; nf < 4; ++nf) cacc[nf][j] *= iq;
  }
  short8 paf[5];
  #pragma unroll
  for (int c = 0; c < 5; ++c)
    #pragma unroll
    for (int j = 0; j < 8; ++j) {
      int r = c * 32 + 8 * lg + j;
      float v = 0.f;
      if (r == 0) v = b0;
      else if (r == 128) v = b1;
      else if (r < 128) {
        int k = q + r - 64;
        if (k >= 0 && k < 512)
          v = __bfloat162float(((const bf16*)mrow)[lr * 132 + r - 1]);
      }
      bf16 vb = __float2bfloat16(v * inv);
      paf[c][j] = (short)__builtin_bit_cast(unsigned short, vb);
    }
  __builtin_amdgcn_s_setprio(1);
  #pragma unroll
  for (int c = 0; c < 5; ++c)
    #pragma unroll
    for (int nf = 0; nf < 4; ++nf) {
      short8 tb = *(const short8*)(tbt + (nf * 16 + lr) * 160 + c * 32 + lg * 8);
      cacc[nf] = __builtin_amdgcn_mfma_f32_16x16x32_bf16(paf[c], tb, cacc[nf], 0, 0, 0);
    }
  __builtin_amdgcn_s_setprio(0);
  #pragma unroll
  for (int nf = 0; nf < 4; ++nf)
    #pragma unroll
    for (int j = 0; j < 4; ++j) {
      int qq = q0 + 4 * lg + j;
      ctx[(long)(qtok0 + qq) * 1024 + h * 64 + nf * 16 + lr] = __float2bfloat16(cacc[nf][j]);
    }
}

// LayerNorm over (y + qo_pooled), output bf16
__global__ __launch_bounds__(256) void k_ln(const float* __restrict__ y,
    const bf16* __restrict__ pooled, const float* __restrict__ g,
    const float* __restrict__ be, bf16* __restrict__ o)
{
  const int row = blockIdx.x, tid = threadIdx.x;
  float x[4], s1 = 0.0f, s2 = 0.0f;
  #pragma unroll
  for (int i = 0; i < 4; ++i) {
    const int c = tid + i * 256;
    x[i] = y[(long)row * 1024 + c] + __bfloat162float(pooled[(long)(4096 + row) * 1024 + c]);
    s1 += x[i]; s2 += x[i] * x[i];
  }
  #pragma unroll
  for (int off = 1; off < 64; off <<= 1) { s1 += __shfl_xor(s1, off); s2 += __shfl_xor(s2, off); }
  __shared__ float r1[4], r2[4];
  if ((tid & 63) == 0) { r1[tid >> 6] = s1; r2[tid >> 6] = s2; }
  __syncthreads();
  s1 = r1[0] + r1[1] + r1[2] + r1[3];
  s2 = r2[0] + r2[1] + r2[2] + r2[3];
  const float mu = s1 * (1.0f / 1024.0f);
  const float var = s2 * (1.0f / 1024.0f) - mu * mu;
  const float rs = rsqrtf(var + 1e-12f);
  #pragma unroll
  for (int i = 0; i < 4; ++i) {
    const int c = tid + i * 256;
    o[(long)row * 1024 + c] = __float2bfloat16((x[i] - mu) * rs * g[c] + be[c]);
  }
}

__global__ void k_sent(float* o, float v) { o[0] = v; }

// ---------------------------------------------------------------------------
extern "C" void kernel_launch(void* const* d_in, const int* in_sizes, int n_in,
                              void* d_out, int out_size, void* d_ws, size_t ws_size,
                              hipStream_t stream)
{
  (void)in_sizes; (void)n_in; (void)out_size;
  const float* seq = (const float*)d_in[0];
  const int*  dl = (const int*)d_in[1];
  const int*  ql = (const int*)d_in[2];
  const int*  ol = (const int*)d_in[3];
  const float* Wq = (const float*)d_in[4];  const float* bq = (const float*)d_in[5];
  const float* Wk = (const float*)d_in[6];  const float* bk = (const float*)d_in[7];
  const float* Wv = (const float*)d_in[8];  const float* bv = (const float*)d_in[9];
  const float* Wp = (const float*)d_in[10]; const float* bp = (const float*)d_in[11];
  const float* Wo = (const float*)d_in[12]; const float* bo = (const float*)d_in[13];
  const float* lng = (const float*)d_in[14]; const float* lnb = (const float*)d_in[15];
  float* out = (float*)d_out;
  char* ws = (char*)d_ws;

  size_t cur = 0;
  auto alloc = [&](size_t bts) { size_t o = cur; cur += (bts + 255) & ~(size_t)255; return o; };
  const size_t oBIAS = alloc(3072 * sizeof(float));
  const size_t oTBL  = alloc(144 * 64 * 2);
  const size_t oTBT  = alloc(64 * 160 * 2);
  const size_t oWBF  = alloc(5ull * 1048576 * 2);
  const size_t oXBF  = alloc(8192ull * 1024 * 2);
  const size_t oQKV  = alloc(8192ull * KQLD * 2);
  const size_t oQR   = alloc(8192ull * 2176 * 2);   // pooled + ybuf region
  const size_t oBP   = alloc(256ull * 64 * 512 * 2);
  if (ws_size < cur) {  // distinctive sentinel: absmax ~ 1e6 + ws MB
    k_sent<<<1, 1, 0, stream>>>(out, 1.0e6f + (float)(ws_size >> 20));
    return;
  }

  float* biasq = (float*)(ws + oBIAS);
  bf16* tbl = (bf16*)(ws + oTBL);
  bf16* tbt = (bf16*)(ws + oTBT);
  bf16* wqb = (bf16*)(ws + oWBF);
  bf16* wpb = wqb + 3 * 1048576;
  bf16* wob = wqb + 4 * 1048576;
  bf16* xbf = (bf16*)(ws + oXBF);
  bf16* qkv = (bf16*)(ws + oQKV);
  bf16* bpb = (bf16*)(ws + oBP);
  bf16* ctx = xbf;                                         // alias: X dead after QKV
  bf16* pooled = (bf16*)(ws + oQR);                        // qR region reuse
  float* ybuf = (float*)(ws + oQR + 8192ull * 1024 * 2);   // after pooled
  bf16* yln = (bf16*)(ws + oBP);                           // alias: Vt dead after attn

  dim3 blk(256);
  // prep: weights cvt + gather + tables/bias in one launch
  k_prep<<<13313, blk, 0, stream>>>(Wq, Wk, Wv, Wp, Wo, wqb,
                                    seq, dl, ql, ol, xbf, tbl, tbt,
                                    bq, bk, bv, biasq);

  // Fused QKV projection (3-buf gemm_big + zero-tile skip): Q|K -> qkv
  // (ldc=2048), V -> Vt (transposed epilogue)
  gemm_big<0, true, true, 1><<<dim3(64, 12, 1), dim3(512), 0, stream>>>(xbf, wqb, qkv, biasq, 3072, 1024, 1024, 1024, KQLD, bpb, dl, ql, ol);
  // fused attention (qR computed in-kernel) -> ctx; 16 waves/block
  k_attn<<<512, dim3(1024), 0, stream>>>(qkv, bpb, tbl, tbt, ctx);

  // poolers on both halves at once: tanh(ctx Wp^T + bp); 1024 blocks = 4/CU
  gemm_64<1, true><<<dim3(128, 8, 1), blk, 0, stream>>>(ctx, wpb, pooled, bp, 1024, 1024, 1024, 1024);
  // y = doc_pooled Wo^T + bo  (f32); 512 blocks
  gemm_64<0, false><<<dim3(64, 8, 1), blk, 0, stream>>>(pooled, wob, ybuf, bo, 1024, 1024, 1024, 1024);
  // LayerNorm(y + qo_pooled)
  k_ln<<<4096, blk, 0, stream>>>(ybuf, pooled, lng, lnb, yln);
  // out = tanh(yln Wp^T + bp)  (f32 to d_out); 512 blocks
  gemm_64<1, false><<<dim3(64, 8, 1), blk, 0, stream>>>(yln, wpb, out, bp, 1024, 1024, 1024, 1024);
}

// Round 13
// 227.843 us; speedup vs baseline: 1.1633x; 1.0387x over previous
//
#include <hip/hip_runtime.h>
#include <hip/hip_bf16.h>
#include <cstdint>
#include <cstddef>

using bf16 = __hip_bfloat16;
typedef __attribute__((ext_vector_type(8))) short short8;
typedef __attribute__((ext_vector_type(4))) short short4v;
typedef __attribute__((ext_vector_type(4))) float f32x4;

#define KQLD 2048             // qkv row stride (Q|K only; V routed to Vt)
#define SCL   0.18033688f     // 0.125 * log2(e): folded into Wq/bq
#define EXP2F(x) __builtin_amdgcn_exp2f(x)   // v_exp_f32 (D = 2^S0)

__device__ __forceinline__ void gl2lds16(const bf16* g, void* l) {
  __builtin_amdgcn_global_load_lds((const __attribute__((address_space(1))) void*)g,
                                   (__attribute__((address_space(3))) void*)l, 16, 0, 0);
}

// ---------------------------------------------------------------------------
// gemm_big: 512 threads, 128x256 tile, 8 waves (2Mx4N), 3-buffer counted-vmcnt
// pipeline (72KB LDS, 2 blocks/CU). VTM=1 (QKV): cols >= 2048 (V) go
// transposed into Vt[z][d][tok], and ZERO-TILE SKIP: M-tiles whose first row
// j0 >= vlen are all-zero in X -> output bit-exactly bias; skip the whole
// K-pipeline (~57% of blocks). XCD-chunked block swizzle (T1).
// ---------------------------------------------------------------------------
template<int ACT, bool OUTBF, bool HASB, int VTM>
__global__ __launch_bounds__(512)
void gemm_big(const bf16* __restrict__ A, const bf16* __restrict__ Bm,
              void* __restrict__ Cv, const float* __restrict__ bias,
              int N, int K, int lda, int ldb, int ldc, bf16* __restrict__ Vt,
              const int* __restrict__ dl, const int* __restrict__ ql,
              const int* __restrict__ ol)
{
  __shared__ __align__(16) short lA[3 * 4096];   // 3 bufs x 8KB  (128x32)
  __shared__ __align__(16) short lB[3 * 8192];   // 3 bufs x 16KB (256x32)
  const int tid = threadIdx.x;
  int bx = blockIdx.x, by = blockIdx.y;
  {
    const int nwg = gridDim.x * gridDim.y;
    if ((nwg & 7) == 0) {                    // bijective XCD chunking
      int n = by * gridDim.x + bx;
      n = (n & 7) * (nwg >> 3) + (n >> 3);
      bx = n / gridDim.y;                    // consecutive n share bx (A panel)
      by = n % gridDim.y;
    }
  }
  const int m0 = bx * 128;
  const int n0 = by * 256;
  const int w = tid >> 6, lane = tid & 63;
  const int wr = (w >> 2) * 64, wc = (w & 3) * 64;
  const int lr = lane & 15, lg = lane >> 4;
  f32x4 acc[4][4] = {};

  bool live = true;
  if (VTM) {
    const int half = m0 >> 12, bb = (m0 >> 9) & 7, j0 = m0 & 511;
    const int vlen = (half == 0) ? dl[bb] : (ql[bb] + ol[bb]);
    live = (j0 < vlen);
  }

  if (live) {
    const int ra = tid >> 2;
    const int xc = ((tid & 3) ^ ((tid >> 2) & 3)) * 8;
    const int e1 = tid + 512;
    const int rb1 = e1 >> 2;
    const bf16* pa0 = A + (long)(m0 + ra) * lda + xc;
    const bf16* pb0 = Bm + (long)(n0 + ra) * ldb + xc;
    const bf16* pb1 = Bm + (long)(n0 + rb1) * ldb + xc;

    #define GSTG(k0_, ofa_, ofb_) do {                  \
      gl2lds16(pa0 + (k0_), &lA[(ofa_) + tid * 8]);     \
      gl2lds16(pb0 + (k0_), &lB[(ofb_) + tid * 8]);     \
      gl2lds16(pb1 + (k0_), &lB[(ofb_) + e1 * 8]);      \
    } while (0)

    const int nT = K >> 5;
    GSTG(0, 0, 0);
    if (nT > 1) GSTG(32, 4096, 8192);
    if (nT > 2) asm volatile("s_waitcnt vmcnt(3)" ::: "memory");
    else        asm volatile("s_waitcnt vmcnt(0)" ::: "memory");
    __builtin_amdgcn_s_barrier();
    __builtin_amdgcn_sched_barrier(0);

    const int lgx = (lg ^ (lr & 3)) * 8;   // swizzled chunk position (shorts)
    int oa = 0, oa1 = 4096, oa2 = 8192;
    int ob = 0, ob1 = 8192, ob2 = 16384;
    for (int t = 0; t < nT; ++t) {
      if (t + 2 < nT) GSTG((t + 2) * 32, oa2, ob2);
      short8 af[4], bfr[4];
      #pragma unroll
      for (int i = 0; i < 4; ++i) {
        af[i]  = *(const short8*)(&lA[oa + (wr + i * 16 + lr) * 32 + lgx]);
        bfr[i] = *(const short8*)(&lB[ob + (wc + i * 16 + lr) * 32 + lgx]);
      }
      #pragma unroll
      for (int mf = 0; mf < 4; ++mf)
        #pragma unroll
        for (int nf = 0; nf < 4; ++nf)
          acc[mf][nf] = __builtin_amdgcn_mfma_f32_16x16x32_bf16(af[mf], bfr[nf], acc[mf][nf], 0, 0, 0);
      if (t + 1 < nT) {
        if (t + 2 < nT) asm volatile("s_waitcnt vmcnt(3)" ::: "memory");
        else            asm volatile("s_waitcnt vmcnt(0)" ::: "memory");
        __builtin_amdgcn_s_barrier();
        __builtin_amdgcn_sched_barrier(0);
        int tmp = oa; oa = oa1; oa1 = oa2; oa2 = tmp;
        tmp = ob; ob = ob1; ob1 = ob2; ob2 = tmp;
      }
    }
    #undef GSTG
  }

  #pragma unroll
  for (int nf = 0; nf < 4; ++nf) {
    const int col = n0 + wc + nf * 16 + lr;
    if (col >= N) continue;
    const float bv = HASB ? bias[col] : 0.0f;
    if (VTM && col >= 2048) {
      const int hd = col - 2048;
      const int d = hd & 63, hh = hd >> 6;
      #pragma unroll
      for (int mf = 0; mf < 4; ++mf) {
        const int row0 = m0 + wr + mf * 16 + lg * 4;
        const int zz = ((1 - (row0 >> 12)) << 7) | (((row0 >> 9) & 7) << 4) | hh;
        short4v pk;
        #pragma unroll
        for (int j = 0; j < 4; ++j)
          pk[j] = (short)__builtin_bit_cast(unsigned short,
                    __float2bfloat16(acc[mf][nf][j] + bv));
        *(short4v*)(Vt + ((long)(zz * 64 + d)) * 512 + (row0 & 511)) = pk;
      }
    } else {
      #pragma unroll
      for (int mf = 0; mf < 4; ++mf) {
        #pragma unroll
        for (int j = 0; j < 4; ++j) {
          const int row = m0 + wr + mf * 16 + lg * 4 + j;
          float x = acc[mf][nf][j] + bv;
          if (ACT == 1) x = tanhf(x);
          const long off = (long)row * ldc + col;
          if (OUTBF) ((bf16*)Cv)[off] = __float2bfloat16(x);
          else       ((float*)Cv)[off] = x;
        }
      }
    }
  }
}

// ---------------------------------------------------------------------------
// gemm_64: 64x128 tile, 256 threads (4 waves, each 64 rows x 32 cols),
// 3-buffer counted-vmcnt pipeline, 36KB LDS -> 4 blocks/CU (16 waves/CU).
// ---------------------------------------------------------------------------
template<int ACT, bool OUTBF>
__global__ __launch_bounds__(256)
void gemm_64(const bf16* __restrict__ A, const bf16* __restrict__ Bm,
             void* __restrict__ Cv, const float* __restrict__ bias,
             int K, int lda, int ldb, int ldc)
{
  __shared__ __align__(16) short lA[3 * 2048];   // 3 bufs x 4KB  (64x32)
  __shared__ __align__(16) short lB[3 * 4096];   // 3 bufs x 8KB  (128x32)
  const int tid = threadIdx.x;
  int bx = blockIdx.x, by = blockIdx.y;
  {
    const int nwg = gridDim.x * gridDim.y;
    if ((nwg & 7) == 0) {                    // bijective XCD chunking
      int n = by * gridDim.x + bx;
      n = (n & 7) * (nwg >> 3) + (n >> 3);
      bx = n / gridDim.y;
      by = n % gridDim.y;
    }
  }
  const int m0 = bx * 64;
  const int n0 = by * 128;
  const int w = tid >> 6, lane = tid & 63;
  const int wc = w * 32;
  const int lr = lane & 15, lg = lane >> 4;
  f32x4 acc[4][2] = {};
  const int rA = tid >> 2, cA = (tid & 3) * 8;
  const bf16* pa  = A + (long)(m0 + rA) * lda + cA;
  const bf16* pb0 = Bm + (long)(n0 + rA) * ldb + cA;
  const bf16* pb1 = Bm + (long)(n0 + 64 + rA) * ldb + cA;

  #define GS64(k0_, oa_, ob_) do {                     \
    gl2lds16(pa  + (k0_), &lA[(oa_) + tid * 8]);       \
    gl2lds16(pb0 + (k0_), &lB[(ob_) + tid * 8]);       \
    gl2lds16(pb1 + (k0_), &lB[(ob_) + 2048 + tid * 8]);\
  } while (0)

  const int nT = K >> 5;
  GS64(0, 0, 0);
  if (nT > 1) GS64(32, 2048, 4096);
  if (nT > 2) asm volatile("s_waitcnt vmcnt(3)" ::: "memory");
  else        asm volatile("s_waitcnt vmcnt(0)" ::: "memory");
  __builtin_amdgcn_s_barrier();
  __builtin_amdgcn_sched_barrier(0);

  int oa = 0, oa1 = 2048, oa2 = 4096;
  int ob = 0, ob1 = 4096, ob2 = 8192;
  for (int t = 0; t < nT; ++t) {
    if (t + 2 < nT) GS64((t + 2) * 32, oa2, ob2);
    short8 af[4], bfr[2];
    #pragma unroll
    for (int i = 0; i < 4; ++i)
      af[i] = *(const short8*)(&lA[oa + (i * 16 + lr) * 32 + lg * 8]);
    #pragma unroll
    for (int j = 0; j < 2; ++j)
      bfr[j] = *(const short8*)(&lB[ob + (wc + j * 16 + lr) * 32 + lg * 8]);
    #pragma unroll
    for (int mf = 0; mf < 4; ++mf)
      #pragma unroll
      for (int nf = 0; nf < 2; ++nf)
        acc[mf][nf] = __builtin_amdgcn_mfma_f32_16x16x32_bf16(af[mf], bfr[nf], acc[mf][nf], 0, 0, 0);
    if (t + 1 < nT) {
      if (t + 2 < nT) asm volatile("s_waitcnt vmcnt(3)" ::: "memory");
      else            asm volatile("s_waitcnt vmcnt(0)" ::: "memory");
      __builtin_amdgcn_s_barrier();
      __builtin_amdgcn_sched_barrier(0);
      int tmp = oa; oa = oa1; oa1 = oa2; oa2 = tmp;
      tmp = ob; ob = ob1; ob1 = ob2; ob2 = tmp;
    }
  }
  #undef GS64

  #pragma unroll
  for (int nf = 0; nf < 2; ++nf) {
    const int col = n0 + wc + nf * 16 + lr;
    const float bv = bias[col];
    #pragma unroll
    for (int mf = 0; mf < 4; ++mf) {
      #pragma unroll
      for (int j = 0; j < 4; ++j) {
        const int row = m0 + mf * 16 + lg * 4 + j;
        float x = acc[mf][nf][j] + bv;
        if (ACT == 1) x = tanhf(x);
        const long off = (long)row * ldc + col;
        if (OUTBF) ((bf16*)Cv)[off] = __float2bfloat16(x);
        else       ((float*)Cv)[off] = x;
      }
    }
  }
}

// ---------------------------------------------------------------------------
// k_prep: one launch for weight-convert (5120 blocks), seq gather (8192),
// and table/bias init (1 block). bf16 outputs packed as short4v 8B stores.
// ---------------------------------------------------------------------------
__global__ __launch_bounds__(256)
void k_prep(const float* __restrict__ w0, const float* __restrict__ w1,
            const float* __restrict__ w2, const float* __restrict__ w3,
            const float* __restrict__ w4, bf16* __restrict__ wdst,
            const float* __restrict__ seq, const int* __restrict__ dl,
            const int* __restrict__ ql, const int* __restrict__ ol,
            bf16* __restrict__ X, bf16* __restrict__ tbl, bf16* __restrict__ tbt,
            const float* __restrict__ bq, const float* __restrict__ bk,
            const float* __restrict__ bv, float* __restrict__ biasq)
{
  const int bid = blockIdx.x, tid = threadIdx.x;
  if (bid < 5120) {
    const int bsel = bid >> 10;
    const float* s = bsel == 0 ? w0 : bsel == 1 ? w1 : bsel == 2 ? w2 : bsel == 3 ? w3 : w4;
    const float sc = (bsel == 0) ? SCL : 1.0f;
    const long loc = ((long)(bid & 1023) * 256 + tid) * 4;
    float4 v = *(const float4*)(s + loc);
    short4v pk;
    pk[0] = (short)__builtin_bit_cast(unsigned short, __float2bfloat16(v.x * sc));
    pk[1] = (short)__builtin_bit_cast(unsigned short, __float2bfloat16(v.y * sc));
    pk[2] = (short)__builtin_bit_cast(unsigned short, __float2bfloat16(v.z * sc));
    pk[3] = (short)__builtin_bit_cast(unsigned short, __float2bfloat16(v.w * sc));
    *(short4v*)(wdst + (long)bsel * 1048576 + loc) = pk;
  } else if (bid < 13312) {
    const int row = bid - 5120;
    const int c = tid * 4;
    const int b = (row >> 9) & 7, j = row & 511;
    int vlen, src;
    if (row < 4096) { vlen = dl[b]; src = (j + 1 > 511) ? 511 : j + 1; }
    else {
      vlen = ql[b] + ol[b];
      int s2 = j + dl[b] + 1;
      src = s2 > 511 ? 511 : (s2 < 0 ? 0 : s2);
    }
    float4 v = make_float4(0, 0, 0, 0);
    if (j < vlen) v = *(const float4*)(seq + ((long)b * 512 + src) * 1024 + c);
    short4v pk;
    pk[0] = (short)__builtin_bit_cast(unsigned short, __float2bfloat16(v.x));
    pk[1] = (short)__builtin_bit_cast(unsigned short, __float2bfloat16(v.y));
    pk[2] = (short)__builtin_bit_cast(unsigned short, __float2bfloat16(v.z));
    pk[3] = (short)__builtin_bit_cast(unsigned short, __float2bfloat16(v.w));
    *(short4v*)(X + (long)row * 1024 + c) = pk;
  } else {
    for (int idx = tid; idx < 144 * 64; idx += 256) {
      const int r = idx >> 6, d = idx & 63;
      float v = 0.0f;
      if (r < 129) {
        const float dv = powf(10000.0f, -(float)(d >> 1) / 32.0f);
        const float a = (float)r * dv;
        v = (d & 1) ? cosf(a) : sinf(a);
      }
      tbl[idx] = __float2bfloat16(v);
    }
    for (int idx = tid; idx < 64 * 160; idx += 256) {
      const int d = idx / 160, rr = idx % 160;
      float v = 0.0f;
      if (rr < 129) {
        const float dv = powf(10000.0f, -(float)(d >> 1) / 32.0f);
        const float a = (float)rr * dv;
        v = (d & 1) ? cosf(a) : sinf(a);
      }
      tbt[idx] = __float2bfloat16(v);
    }
    for (int idx = tid; idx < 3072; idx += 256) {
      float v = (idx < 1024) ? bq[idx] * SCL : (idx < 2048) ? bk[idx - 1024] : bv[idx - 2048];
      biasq[idx] = v;
    }
  }
}

// ---------------------------------------------------------------------------
// Fused NeZha attention (log2-domain, no max tracking). 16-wave version with
// PAD-KEY ANALYTIC PATH: the K-segment's valid length vk is block-uniform
// (attn=0 -> ql+ol<=198, attn=1 -> dl<=299). Keys k>=vk have K=bf16(bk),
// V=bf16(bv) exactly (zero gather rows + bias), so only nLive=ceil(vk/64)<=5
// k-tiles run the full staged QK/PV pipeline (last live tile's internal
// padding is exact via the normal path). Remaining tiles are analytic:
// score == s_pad = Q[q].K[511] (row 511 always padded), computed once per q;
// cls 0/2 pad tiles collapse to a constant-P update; band-overlap pad tiles
// run the per-element bucket/band code with s_pad; PV contribution is rank-1
// (sum of bf16-rounded pad P) * bf16(bv), added before normalization.
// ---------------------------------------------------------------------------
__global__ __launch_bounds__(1024, 4)
void k_attn(const bf16* __restrict__ QKV, const bf16* __restrict__ Vt,
            const bf16* __restrict__ tbl, const bf16* __restrict__ tbt,
            const float* __restrict__ biasq, const int* __restrict__ dl,
            const int* __restrict__ ql, const int* __restrict__ ol,
            bf16* __restrict__ ctx)
{
  __shared__ __align__(16) unsigned short s_kv[16384];          // K0|K1|V0|V1 swizzled (32 KB)
  __shared__ __align__(16) unsigned short s_ptile[16][16 * 72]; // 36864 B
  __shared__ __align__(16) unsigned short s_m[16][16 * 132];    // qrow ∪ band, 67584 B

  const int tid = threadIdx.x;
  const int wv = tid >> 6, lane = tid & 63;
  const int lr = lane & 15, lg = lane >> 4;
  const int bid = blockIdx.x;
  const int xcd = bid & 7;
  const int idx = bid >> 3;                 // 0..63
  const int z = (xcd << 5) | (idx >> 1);    // 0..255; same-z pair on same XCD
  const int g = idx & 1;                    // which half of the 8 qsegs
  const int attn = z >> 7, b = (z >> 4) & 7, h = z & 15;
  const int qtok0 = attn * 4096 + b * 512;
  const int ktok0 = (1 - attn) * 4096 + b * 512;
  const int q0 = g * 256 + wv * 16;         // wave's 16 q-rows
  const int q = q0 + lr;

  // valid length of the KEY segment (block-uniform)
  const int vk = (attn == 0) ? (ql[b] + ol[b]) : dl[b];
  int nLive = (vk + 63) >> 6;
  if (nLive < 1) nLive = 1;
  if (nLive > 8) nLive = 8;

  unsigned short* ptile = s_ptile[wv];
  unsigned short* mrow  = s_m[wv];

  const bf16* Kbase = QKV + (long)ktok0 * KQLD + 1024 + h * 64;
  const bf16* Vbase = Vt + (long)z * (64 * 512);

  const int sl = tid & 511;
  const int rs = sl >> 3, cs = (sl & 7) * 8;
  const int scz = cs ^ ((rs & 7) << 3);
  const bool isV = tid >= 512;

  short8 qf[2], kp[2];
  #pragma unroll
  for (int hh = 0; hh < 2; ++hh) {
    qf[hh] = *(const short8*)(QKV + (long)(qtok0 + q0 + lr) * KQLD + h * 64 + hh * 32 + lg * 8);
    kp[hh] = *(const short8*)(Kbase + (long)511 * KQLD + hh * 32 + lg * 8);  // pad K row
  }

  #define STAGE(kvb_, koff_, voff_) do {                                            \
    if (!isV) gl2lds16(Kbase + (long)((kvb_) + rs) * KQLD + scz, &s_kv[(koff_) + sl * 8]); \
    else      gl2lds16(Vbase + (long)rs * 512 + (kvb_) + scz,    &s_kv[(voff_) + sl * 8]); \
  } while (0)

  STAGE(0, 0, 8192);   // prologue: tile 0 -> buf0 (overlaps qR compute below)

  #pragma unroll
  for (int rt = 0; rt < 9; ++rt) {
    f32x4 qa = {};
    #pragma unroll
    for (int hh = 0; hh < 2; ++hh) {
      short8 ta = *(const short8*)(tbl + (rt * 16 + lr) * 64 + hh * 32 + lg * 8);
      qa = __builtin_amdgcn_mfma_f32_16x16x32_bf16(ta, qf[hh], qa, 0, 0, 0);
    }
    if (rt < 8 || lg == 0) {
      short4v pk;
      #pragma unroll
      for (int j = 0; j < 4; ++j)
        pk[j] = (short)__builtin_bit_cast(unsigned short, __float2bfloat16(qa[j]));
      *(short4v*)(&mrow[lr * 132 + rt * 16 + lg * 4]) = pk;
    }
  }

  // s_pad = Q[q] . K_pad  (per q = lr; reduce the 4-lane d-partials)
  float sp = 0.f;
  #pragma unroll
  for (int hh = 0; hh < 2; ++hh)
    #pragma unroll
    for (int j = 0; j < 8; ++j)
      sp += __bfloat162float(__builtin_bit_cast(bf16, (unsigned short)qf[hh][j])) *
            __bfloat162float(__builtin_bit_cast(bf16, (unsigned short)kp[hh][j]));
  sp += __shfl_xor(sp, 16); sp += __shfl_xor(sp, 32);
  const float s_pad = sp;

  const int hx = (lr >> 2) & 1;
  const int lgx8 = (lg ^ (lr & 3)) * 8;
  const int lrx64 = lr * 64;

  const float bias_lo = __bfloat162float(((const bf16*)mrow)[lr * 132 + 0]);
  const float bias_hi = __bfloat162float(((const bf16*)mrow)[lr * 132 + 128]);

  float l_run = 0.f, b0 = 0.f, b1 = 0.f, pad_ps = 0.f;
  f32x4 cacc[4] = {};

  __syncthreads();   // tile 0 staged (vmcnt drained)

  // ---- live k-tiles (full pipeline)
  for (int t = 0; t < nLive; ++t) {
    const int kvb = t * 64;
    const int koff = (t & 1) * 4096;
    const int voff = 8192 + koff;
    if (t + 1 < nLive) { const int nk = ((t + 1) & 1) * 4096; STAGE(kvb + 64, nk, 8192 + nk); }

    f32x4 sc[4] = {};
    __builtin_amdgcn_s_setprio(1);
    #pragma unroll
    for (int hh = 0; hh < 2; ++hh) {
      const int cb = ((hh ^ hx) << 5) + lgx8;
      #pragma unroll
      for (int kb4 = 0; kb4 < 4; ++kb4) {
        short8 ak = *(const short8*)(&s_kv[koff + kb4 * 1024 + lrx64 + cb]);
        sc[kb4] = __builtin_amdgcn_mfma_f32_16x16x32_bf16(ak, qf[hh], sc[kb4], 0, 0, 0);
      }
    }
    __builtin_amdgcn_s_setprio(0);

    const int cls = (kvb + 63 <= q0 - 64) ? 0 : ((kvb >= q0 + 79) ? 2 : 1);

    float pacc[4];
    if (cls == 1) {
      const bool eLo = (kvb <= q0 - 49);
      const bool eHi = (kvb + 63 >= q0 + 64);
      short4v pks[4];
      #pragma unroll
      for (int kb4 = 0; kb4 < 4; ++kb4) {
        short4v pk;
        float ps = 0.f;
        #pragma unroll
        for (int j = 0; j < 4; ++j) {
          int rel = kvb + kb4 * 16 + 4 * lg + j - q;
          int rc = rel < -64 ? -64 : (rel > 64 ? 64 : rel);
          float bias = __bfloat162float(((const bf16*)mrow)[lr * 132 + rc + 64]);
          float p = EXP2F(sc[kb4][j] + bias);
          ps += p;
          if (eLo && rel <= -64) b0 += p;
          if (eHi && rel >= 64)  b1 += p;
          pk[j] = (short)__builtin_bit_cast(unsigned short, __float2bfloat16(p));
        }
        pks[kb4] = pk;
        pacc[kb4] = ps;
        *(short4v*)(&ptile[lr * 72 + kb4 * 16 + 4 * lg]) = pk;
      }
      l_run += (pacc[0] + pacc[1]) + (pacc[2] + pacc[3]);
      #pragma unroll
      for (int kb4 = 0; kb4 < 4; ++kb4)
        #pragma unroll
        for (int j = 0; j < 4; ++j) {
          int rel = kvb + kb4 * 16 + 4 * lg + j - q;
          if (rel > -64 && rel < 64)
            mrow[lr * 132 + rel + 63] = (unsigned short)pks[kb4][j];
        }
    } else {
      const float bc = (cls == 0) ? bias_lo : bias_hi;
      #pragma unroll
      for (int kb4 = 0; kb4 < 4; ++kb4) {
        short4v pk;
        float ps = 0.f;
        #pragma unroll
        for (int j = 0; j < 4; ++j) {
          float p = EXP2F(sc[kb4][j] + bc);
          ps += p;
          pk[j] = (short)__builtin_bit_cast(unsigned short, __float2bfloat16(p));
        }
        pacc[kb4] = ps;
        *(short4v*)(&ptile[lr * 72 + kb4 * 16 + 4 * lg]) = pk;
      }
      const float ts = (pacc[0] + pacc[1]) + (pacc[2] + pacc[3]);
      l_run += ts;
      if (cls == 0) b0 += ts; else b1 += ts;
    }

    __builtin_amdgcn_s_setprio(1);
    #pragma unroll
    for (int c2 = 0; c2 < 2; ++c2) {
      short8 pa = *(const short8*)(&ptile[lr * 72 + c2 * 32 + lg * 8]);
      const int cb = ((c2 ^ hx) << 5) + lgx8;
      #pragma unroll
      for (int nf = 0; nf < 4; ++nf) {
        short8 vb = *(const short8*)(&s_kv[voff + nf * 1024 + lrx64 + cb]);
        cacc[nf] = __builtin_amdgcn_mfma_f32_16x16x32_bf16(pa, vb, cacc[nf], 0, 0, 0);
      }
    }
    __builtin_amdgcn_s_setprio(0);
    __syncthreads();
  }
  #undef STAGE

  // ---- pad k-tiles: score == s_pad for every key; no staging/MFMA/barriers
  for (int t = nLive; t < 8; ++t) {
    const int kvb = t * 64;
    const int cls = (kvb + 63 <= q0 - 64) ? 0 : ((kvb >= q0 + 79) ? 2 : 1);
    if (cls == 1) {
      const bool eLo = (kvb <= q0 - 49);
      const bool eHi = (kvb + 63 >= q0 + 64);
      short4v pks[4];
      float pacc[4];
      #pragma unroll
      for (int kb4 = 0; kb4 < 4; ++kb4) {
        short4v pk;
        float ps = 0.f;
        #pragma unroll
        for (int j = 0; j < 4; ++j) {
          int rel = kvb + kb4 * 16 + 4 * lg + j - q;
          int rc = rel < -64 ? -64 : (rel > 64 ? 64 : rel);
          float bias = __bfloat162float(((const bf16*)mrow)[lr * 132 + rc + 64]);
          float p = EXP2F(s_pad + bias);
          ps += p;
          if (eLo && rel <= -64) b0 += p;
          if (eHi && rel >= 64)  b1 += p;
          bf16 pb = __float2bfloat16(p);
          pad_ps += __bfloat162float(pb);
          pk[j] = (short)__builtin_bit_cast(unsigned short, pb);
        }
        pks[kb4] = pk;
        pacc[kb4] = ps;
      }
      l_run += (pacc[0] + pacc[1]) + (pacc[2] + pacc[3]);
      #pragma unroll
      for (int kb4 = 0; kb4 < 4; ++kb4)
        #pragma unroll
        for (int j = 0; j < 4; ++j) {
          int rel = kvb + kb4 * 16 + 4 * lg + j - q;
          if (rel > -64 && rel < 64)
            mrow[lr * 132 + rel + 63] = (unsigned short)pks[kb4][j];
        }
    } else {
      const float bc = (cls == 0) ? bias_lo : bias_hi;
      const float p = EXP2F(s_pad + bc);
      const float ts = 16.0f * p;            // exact (x16)
      l_run += ts;
      if (cls == 0) b0 += ts; else b1 += ts;
      pad_ps += 16.0f * __bfloat162float(__float2bfloat16(p));
    }
  }

  // ---- finalize softmax stats (4 lanes share q)
  l_run += __shfl_xor(l_run, 16); l_run += __shfl_xor(l_run, 32);
  b0 += __shfl_xor(b0, 16); b0 += __shfl_xor(b0, 32);
  b1 += __shfl_xor(b1, 16); b1 += __shfl_xor(b1, 32);
  pad_ps += __shfl_xor(pad_ps, 16); pad_ps += __shfl_xor(pad_ps, 32);
  const float inv = 1.0f / l_run;

  // ---- pad rank-1 PV + normalize ctx
  float vv[4];
  #pragma unroll
  for (int nf = 0; nf < 4; ++nf)
    vv[nf] = __bfloat162float(__float2bfloat16(biasq[2048 + h * 64 + nf * 16 + lr]));
  #pragma unroll
  for (int j = 0; j < 4; ++j) {
    float iq = __shfl(inv, 4 * lg + j);
    float pq = __shfl(pad_ps, 4 * lg + j);
    #pragma unroll
    for (int nf = 0; nf < 4; ++nf)
      cacc[nf][j] = (cacc[nf][j] + pq * vv[nf]) * iq;
  }
  // ---- pr A-fragments: pr[q=lr][r = 32c+8lg+j]
  short8 paf[5];
  #pragma unroll
  for (int c = 0; c < 5; ++c)
    #pragma unroll
    for (int j = 0; j < 8; ++j) {
      int r = c * 32 + 8 * lg + j;
      float v = 0.f;
      if (r == 0) v = b0;
      else if (r == 128) v = b1;
      else if (r < 128) {
        int k = q + r - 64;
        if (k >= 0 && k < 512)
          v = __bfloat162float(((const bf16*)mrow)[lr * 132 + r - 1]);
      }
      bf16 vb = __float2bfloat16(v * inv);
      paf[c][j] = (short)__builtin_bit_cast(unsigned short, vb);
    }
  // ---- rel-value: ctx += pr @ table^T
  __builtin_amdgcn_s_setprio(1);
  #pragma unroll
  for (int c = 0; c < 5; ++c)
    #pragma unroll
    for (int nf = 0; nf < 4; ++nf) {
      short8 tb = *(const short8*)(tbt + (nf * 16 + lr) * 160 + c * 32 + lg * 8);
      cacc[nf] = __builtin_amdgcn_mfma_f32_16x16x32_bf16(paf[c], tb, cacc[nf], 0, 0, 0);
    }
  __builtin_amdgcn_s_setprio(0);
  // ---- write ctx (stride 1024): lane holds (q = q0+4lg+j, d = nf*16+lr)
  #pragma unroll
  for (int nf = 0; nf < 4; ++nf)
    #pragma unroll
    for (int j = 0; j < 4; ++j) {
      int qq = q0 + 4 * lg + j;
      ctx[(long)(qtok0 + qq) * 1024 + h * 64 + nf * 16 + lr] = __float2bfloat16(cacc[nf][j]);
    }
}

// LayerNorm over (y + qo_pooled), output bf16
__global__ __launch_bounds__(256) void k_ln(const float* __restrict__ y,
    const bf16* __restrict__ pooled, const float* __restrict__ g,
    const float* __restrict__ be, bf16* __restrict__ o)
{
  const int row = blockIdx.x, tid = threadIdx.x;
  float x[4], s1 = 0.0f, s2 = 0.0f;
  #pragma unroll
  for (int i = 0; i < 4; ++i) {
    const int c = tid + i * 256;
    x[i] = y[(long)row * 1024 + c] + __bfloat162float(pooled[(long)(4096 + row) * 1024 + c]);
    s1 += x[i]; s2 += x[i] * x[i];
  }
  #pragma unroll
  for (int off = 1; off < 64; off <<= 1) { s1 += __shfl_xor(s1, off); s2 += __shfl_xor(s2, off); }
  __shared__ float r1[4], r2[4];
  if ((tid & 63) == 0) { r1[tid >> 6] = s1; r2[tid >> 6] = s2; }
  __syncthreads();
  s1 = r1[0] + r1[1] + r1[2] + r1[3];
  s2 = r2[0] + r2[1] + r2[2] + r2[3];
  const float mu = s1 * (1.0f / 1024.0f);
  const float var = s2 * (1.0f / 1024.0f) - mu * mu;
  const float rs = rsqrtf(var + 1e-12f);
  #pragma unroll
  for (int i = 0; i < 4; ++i) {
    const int c = tid + i * 256;
    o[(long)row * 1024 + c] = __float2bfloat16((x[i] - mu) * rs * g[c] + be[c]);
  }
}

__global__ void k_sent(float* o, float v) { o[0] = v; }

// ---------------------------------------------------------------------------
extern "C" void kernel_launch(void* const* d_in, const int* in_sizes, int n_in,
                              void* d_out, int out_size, void* d_ws, size_t ws_size,
                              hipStream_t stream)
{
  (void)in_sizes; (void)n_in; (void)out_size;
  const float* seq = (const float*)d_in[0];
  const int*  dl = (const int*)d_in[1];
  const int*  ql = (const int*)d_in[2];
  const int*  ol = (const int*)d_in[3];
  const float* Wq = (const float*)d_in[4];  const float* bq = (const float*)d_in[5];
  const float* Wk = (const float*)d_in[6];  const float* bk = (const float*)d_in[7];
  const float* Wv = (const float*)d_in[8];  const float* bv = (const float*)d_in[9];
  const float* Wp = (const float*)d_in[10]; const float* bp = (const float*)d_in[11];
  const float* Wo = (const float*)d_in[12]; const float* bo = (const float*)d_in[13];
  const float* lng = (const float*)d_in[14]; const float* lnb = (const float*)d_in[15];
  float* out = (float*)d_out;
  char* ws = (char*)d_ws;

  size_t cur = 0;
  auto alloc = [&](size_t bts) { size_t o = cur; cur += (bts + 255) & ~(size_t)255; return o; };
  const size_t oBIAS = alloc(3072 * sizeof(float));
  const size_t oTBL  = alloc(144 * 64 * 2);
  const size_t oTBT  = alloc(64 * 160 * 2);
  const size_t oWBF  = alloc(5ull * 1048576 * 2);
  const size_t oXBF  = alloc(8192ull * 1024 * 2);
  const size_t oQKV  = alloc(8192ull * KQLD * 2);
  const size_t oQR   = alloc(8192ull * 2176 * 2);   // pooled + ybuf region
  const size_t oBP   = alloc(256ull * 64 * 512 * 2);
  if (ws_size < cur) {  // distinctive sentinel: absmax ~ 1e6 + ws MB
    k_sent<<<1, 1, 0, stream>>>(out, 1.0e6f + (float)(ws_size >> 20));
    return;
  }

  float* biasq = (float*)(ws + oBIAS);
  bf16* tbl = (bf16*)(ws + oTBL);
  bf16* tbt = (bf16*)(ws + oTBT);
  bf16* wqb = (bf16*)(ws + oWBF);
  bf16* wpb = wqb + 3 * 1048576;
  bf16* wob = wqb + 4 * 1048576;
  bf16* xbf = (bf16*)(ws + oXBF);
  bf16* qkv = (bf16*)(ws + oQKV);
  bf16* bpb = (bf16*)(ws + oBP);
  bf16* ctx = xbf;                                         // alias: X dead after QKV
  bf16* pooled = (bf16*)(ws + oQR);                        // qR region reuse
  float* ybuf = (float*)(ws + oQR + 8192ull * 1024 * 2);   // after pooled
  bf16* yln = (bf16*)(ws + oBP);                           // alias: Vt dead after attn

  dim3 blk(256);
  // prep: weights cvt + gather + tables/bias in one launch
  k_prep<<<13313, blk, 0, stream>>>(Wq, Wk, Wv, Wp, Wo, wqb,
                                    seq, dl, ql, ol, xbf, tbl, tbt,
                                    bq, bk, bv, biasq);

  // Fused QKV projection (3-buf gemm_big + zero-tile skip): Q|K -> qkv
  // (ldc=2048), V -> Vt (transposed epilogue)
  gemm_big<0, true, true, 1><<<dim3(64, 12, 1), dim3(512), 0, stream>>>(xbf, wqb, qkv, biasq, 3072, 1024, 1024, 1024, KQLD, bpb, dl, ql, ol);
  // fused attention (pad-key analytic path) -> ctx; 16 waves/block
  k_attn<<<512, dim3(1024), 0, stream>>>(qkv, bpb, tbl, tbt, biasq, dl, ql, ol, ctx);

  // poolers on both halves at once: tanh(ctx Wp^T + bp); 1024 blocks = 4/CU
  gemm_64<1, true><<<dim3(128, 8, 1), blk, 0, stream>>>(ctx, wpb, pooled, bp, 1024, 1024, 1024, 1024);
  // y = doc_pooled Wo^T + bo  (f32); 512 blocks
  gemm_64<0, false><<<dim3(64, 8, 1), blk, 0, stream>>>(pooled, wob, ybuf, bo, 1024, 1024, 1024, 1024);
  // LayerNorm(y + qo_pooled)
  k_ln<<<4096, blk, 0, stream>>>(ybuf, pooled, lng, lnb, yln);
  // out = tanh(yln Wp^T + bp)  (f32 to d_out); 512 blocks
  gemm_64<1, false><<<dim3(64, 8, 1), blk, 0, stream>>>(yln, wpb, out, bp, 1024, 1024, 1024, 1024);
}